// Round 8
// baseline (552.519 us; speedup 1.0000x reference)
//
#include <hip/hip_runtime.h>
#include <hip/hip_bf16.h>

#define N_NODES 50000
#define N_EDGES 800000
#define F_IN 256
#define HID 64
#define HEADS 4
#define NEG 0.2f
#define LN_EPS 1e-5f

typedef _Float16 half8 __attribute__((ext_vector_type(8)));
typedef _Float16 half4v __attribute__((ext_vector_type(4)));
typedef float floatx4 __attribute__((ext_vector_type(4)));

__device__ __forceinline__ float wave_sum(float v) {
    #pragma unroll
    for (int o = 32; o > 0; o >>= 1) v += __shfl_xor(v, o, 64);
    return v;
}
__device__ __forceinline__ int wave_sum_i(int v) {
    #pragma unroll
    for (int o = 32; o > 0; o >>= 1) v += __shfl_xor(v, o, 64);
    return v;
}
__device__ __forceinline__ float leaky(float x) { return x > 0.0f ? x : NEG * x; }

// ---------------- CSR build ----------------
__global__ void count_kernel(const int* __restrict__ dst, int* __restrict__ deg,
                             int E, int Etot) {
    int e = blockIdx.x * blockDim.x + threadIdx.x;
    if (e >= Etot) return;
    int d = (e < E) ? dst[e] : (e - E);   // tail = self loops
    atomicAdd(&deg[d], 1);
}

__global__ void scan_part(const int* __restrict__ deg, int* __restrict__ bsum, int N) {
    int tid = threadIdx.x;
    int i = blockIdx.x * 256 + tid;
    int v = (i < N) ? deg[i] : 0;
    int s = wave_sum_i(v);
    __shared__ int ws4[4];
    if ((tid & 63) == 0) ws4[tid >> 6] = s;
    __syncthreads();
    if (tid == 0) bsum[blockIdx.x] = ws4[0] + ws4[1] + ws4[2] + ws4[3];
}

__global__ void scan_top(int* __restrict__ bsum, int nb) {   // in-place exclusive
    __shared__ int sh[256];
    int t = threadIdx.x;
    int v = (t < nb) ? bsum[t] : 0;
    sh[t] = v;
    __syncthreads();
    for (int o = 1; o < 256; o <<= 1) {
        int u = (t >= o) ? sh[t - o] : 0;
        __syncthreads();
        sh[t] += u;
        __syncthreads();
    }
    if (t < nb) bsum[t] = sh[t] - v;    // exclusive
}

__global__ void scan_final(const int* __restrict__ deg, const int* __restrict__ bsum,
                           int* __restrict__ row_ptr, int N) {
    __shared__ int sh[256];
    int t = threadIdx.x;
    int i = blockIdx.x * 256 + t;
    int v = (i < N) ? deg[i] : 0;
    sh[t] = v;
    __syncthreads();
    for (int o = 1; o < 256; o <<= 1) {
        int u = (t >= o) ? sh[t - o] : 0;
        __syncthreads();
        sh[t] += u;
        __syncthreads();
    }
    if (i < N) row_ptr[i + 1] = bsum[blockIdx.x] + sh[t];   // inclusive prefix
    if (i == 0) row_ptr[0] = 0;
}

__global__ void scatter_kernel(const int* __restrict__ src, const int* __restrict__ dst,
                               const int* __restrict__ row_ptr, int* __restrict__ fill,
                               int* __restrict__ col, int E, int Etot) {
    int e = blockIdx.x * blockDim.x + threadIdx.x;
    if (e >= Etot) return;
    int s, d;
    if (e < E) { s = src[e]; d = dst[e]; }
    else       { s = d = e - E; }
    int pos = atomicAdd(&fill[d], 1);
    col[row_ptr[d] + pos] = s;
}

// ---------------- merged fp32 -> fp16 conversion over 5 ranges ----------------
struct CvtJob { const float* src; _Float16* dst; int len; };
__global__ void cvt_f16_multi(CvtJob j0, CvtJob j1, CvtJob j2, CvtJob j3, CvtJob j4) {
    int idx = (blockIdx.x * blockDim.x + threadIdx.x) * 4;
    const float* s; _Float16* d; int rel = idx;
    if      (rel < j0.len) { s = j0.src; d = j0.dst; }
    else if ((rel -= j0.len) < j1.len) { s = j1.src; d = j1.dst; }
    else if ((rel -= j1.len) < j2.len) { s = j2.src; d = j2.dst; }
    else if ((rel -= j2.len) < j3.len) { s = j3.src; d = j3.dst; }
    else if ((rel -= j3.len) < j4.len) { s = j4.src; d = j4.dst; }
    else return;
    float4 v = *(const float4*)(s + rel);
    half4v h;
    h[0] = (_Float16)v.x; h[1] = (_Float16)v.y;
    h[2] = (_Float16)v.z; h[3] = (_Float16)v.w;
    *(half4v*)(d + rel) = h;
}

// ---------------- gemm1 fused: h1h = xh@W1^T (+att epilogue) AND lin = xh@lin_w^T + lin_b ----
// LDS-staged coalesced epilogue: fragment->LDS scatter (cheap), then 1KB/issue dwordx4
// stores (full-line coverage; avoids the 5.6x partial-line write amplification seen in R7).
__global__ void gemm1_fused(const _Float16* __restrict__ A, const _Float16* __restrict__ B1,
                            const _Float16* __restrict__ B2, const float* __restrict__ lin_b,
                            _Float16* __restrict__ h1h, float* __restrict__ lin,
                            const float* __restrict__ att_s, const float* __restrict__ att_d,
                            float* __restrict__ a_srcO, float* __restrict__ a_dstO, int M) {
    const int K = 256;
    __shared__ __align__(16) char smem[4 * 8192 + 4 * 4096];   // 4x 16x256 f16 + 4x 16x64 f32
    int w = threadIdx.x >> 6, lane = threadIdx.x & 63;
    int m_base = blockIdx.x * 64 + w * 16;
    if (m_base >= M) return;
    int r = lane & 15, q = lane >> 4;
    const _Float16* ap = A + (size_t)(m_base + r) * K + q * 8;
    const _Float16* b1p = B1 + (size_t)r * K + q * 8;
    const _Float16* b2p = B2 + (size_t)r * K + q * 8;
    floatx4 acc[20];
    #pragma unroll
    for (int t = 0; t < 20; ++t) acc[t] = (floatx4){0.f, 0.f, 0.f, 0.f};
    for (int k0 = 0; k0 < K; k0 += 32) {
        half8 a = *(const half8*)(ap + k0);
        #pragma unroll
        for (int t = 0; t < 16; ++t) {
            half8 b = *(const half8*)(b1p + (size_t)t * 16 * K + k0);
            acc[t] = __builtin_amdgcn_mfma_f32_16x16x32_f16(a, b, acc[t], 0, 0, 0);
        }
        #pragma unroll
        for (int t = 0; t < 4; ++t) {
            half8 b = *(const half8*)(b2p + (size_t)t * 16 * K + k0);
            acc[16 + t] = __builtin_amdgcn_mfma_f32_16x16x32_f16(a, b, acc[16 + t], 0, 0, 0);
        }
    }
    // stage h1h tile (per-wave LDS region; no cross-wave sharing -> no barrier)
    _Float16* sth = (_Float16*)(smem + w * 8192);
    #pragma unroll
    for (int t = 0; t < 16; ++t)
        #pragma unroll
        for (int rr = 0; rr < 4; ++rr)
            sth[(q * 4 + rr) * 256 + t * 16 + r] = (_Float16)acc[t][rr];
    // stage lin tile (+bias)
    float* stl = (float*)(smem + 32768 + w * 4096);
    #pragma unroll
    for (int t = 0; t < 4; ++t) {
        float bv = lin_b[t * 16 + r];
        #pragma unroll
        for (int rr = 0; rr < 4; ++rr)
            stl[(q * 4 + rr) * 64 + t * 16 + r] = acc[16 + t][rr] + bv;
    }
    // coalesced writeback: 16 rows x 512B contiguous (h1h), 16 rows x 256B (lin)
    {
        const int4* src = (const int4*)sth;
        int4* dst = (int4*)((char*)h1h + (size_t)m_base * 512);
        #pragma unroll
        for (int i = 0; i < 8; ++i) dst[i * 64 + lane] = src[i * 64 + lane];
        const int4* srcl = (const int4*)stl;
        int4* dstl = (int4*)((char*)lin + (size_t)m_base * 256);
        #pragma unroll
        for (int i = 0; i < 4; ++i) dstl[i * 64 + lane] = srcl[i * 64 + lane];
    }
    // att epilogue (H=4) from acc[0..15]
    float ps[4][4], pd[4][4];
    #pragma unroll
    for (int h = 0; h < 4; ++h) {
        #pragma unroll
        for (int rr = 0; rr < 4; ++rr) { ps[h][rr] = 0.f; pd[h][rr] = 0.f; }
        #pragma unroll
        for (int tt = 0; tt < 4; ++tt) {
            int t = h * 4 + tt;
            float as = att_s[t * 16 + r];
            float ad = att_d[t * 16 + r];
            #pragma unroll
            for (int rr = 0; rr < 4; ++rr) {
                ps[h][rr] += acc[t][rr] * as;
                pd[h][rr] += acc[t][rr] * ad;
            }
        }
    }
    #pragma unroll
    for (int m = 1; m < 16; m <<= 1) {
        #pragma unroll
        for (int h = 0; h < 4; ++h)
            #pragma unroll
            for (int rr = 0; rr < 4; ++rr) {
                ps[h][rr] += __shfl_xor(ps[h][rr], m, 64);
                pd[h][rr] += __shfl_xor(pd[h][rr], m, 64);
            }
    }
    if (r == 0) {
        #pragma unroll
        for (int rr = 0; rr < 4; ++rr) {
            int gm = m_base + q * 4 + rr;
            #pragma unroll
            for (int h = 0; h < 4; ++h) {
                a_srcO[gm * 4 + h] = ps[h][rr];
                a_dstO[gm * 4 + h] = pd[h][rr];
            }
        }
    }
}

// ---------------- generic fp16 MFMA GEMM + optional att epilogue (LDS-staged stores) -----
template<int NT, int H, typename OutT>
__global__ void gemm_mfma(const _Float16* __restrict__ A, const _Float16* __restrict__ B,
                          const float* __restrict__ bias, OutT* __restrict__ Cout,
                          const float* __restrict__ att_s, const float* __restrict__ att_d,
                          float* __restrict__ a_srcO, float* __restrict__ a_dstO,
                          int M, int K, int add_bias) {
    constexpr int TILEB = 16 * NT * 16 * sizeof(OutT);   // per-wave staged bytes
    __shared__ __align__(16) char smem[4 * TILEB];
    int w = threadIdx.x >> 6, lane = threadIdx.x & 63;
    int m_base = blockIdx.x * 64 + w * 16;
    if (m_base >= M) return;
    int r = lane & 15, q = lane >> 4;
    const _Float16* ap = A + (size_t)(m_base + r) * K + q * 8;
    const _Float16* bp = B + (size_t)r * K + q * 8;
    floatx4 acc[NT];
    #pragma unroll
    for (int t = 0; t < NT; ++t) acc[t] = (floatx4){0.f, 0.f, 0.f, 0.f};
    for (int k0 = 0; k0 < K; k0 += 32) {
        half8 a = *(const half8*)(ap + k0);
        #pragma unroll
        for (int t = 0; t < NT; ++t) {
            half8 b = *(const half8*)(bp + (size_t)t * 16 * K + k0);
            acc[t] = __builtin_amdgcn_mfma_f32_16x16x32_f16(a, b, acc[t], 0, 0, 0);
        }
    }
    const int Nc = NT * 16;
    OutT* st = (OutT*)(smem + w * TILEB);
    #pragma unroll
    for (int t = 0; t < NT; ++t) {
        int cc = t * 16 + r;
        float bv = add_bias ? bias[cc] : 0.0f;
        #pragma unroll
        for (int rr = 0; rr < 4; ++rr)
            st[(q * 4 + rr) * Nc + cc] = (OutT)(acc[t][rr] + bv);
    }
    {
        constexpr int NISS = TILEB / 1024;               // 1KB coalesced issues
        const int4* src = (const int4*)st;
        int4* dst = (int4*)((char*)Cout + (size_t)m_base * (Nc * sizeof(OutT)));
        #pragma unroll
        for (int i = 0; i < NISS; ++i) dst[i * 64 + lane] = src[i * 64 + lane];
    }
    if constexpr (H > 0) {
        float ps[H][4], pd[H][4];
        #pragma unroll
        for (int h = 0; h < H; ++h) {
            #pragma unroll
            for (int rr = 0; rr < 4; ++rr) { ps[h][rr] = 0.f; pd[h][rr] = 0.f; }
            #pragma unroll
            for (int tt = 0; tt < 4; ++tt) {
                int t = h * 4 + tt;
                float as = att_s[t * 16 + r];
                float ad = att_d[t * 16 + r];
                #pragma unroll
                for (int rr = 0; rr < 4; ++rr) {
                    ps[h][rr] += acc[t][rr] * as;
                    pd[h][rr] += acc[t][rr] * ad;
                }
            }
        }
        #pragma unroll
        for (int m = 1; m < 16; m <<= 1) {
            #pragma unroll
            for (int h = 0; h < H; ++h)
                #pragma unroll
                for (int rr = 0; rr < 4; ++rr) {
                    ps[h][rr] += __shfl_xor(ps[h][rr], m, 64);
                    pd[h][rr] += __shfl_xor(pd[h][rr], m, 64);
                }
        }
        if (r == 0) {
            #pragma unroll
            for (int rr = 0; rr < 4; ++rr) {
                int gm = m_base + q * 4 + rr;
                #pragma unroll
                for (int h = 0; h < H; ++h) {
                    a_srcO[gm * H + h] = ps[h][rr];
                    a_dstO[gm * H + h] = pd[h][rr];
                }
            }
        }
    }
}

// ---------------- GAT aggregation, H=4: premultiplied LDS alphas, scalar row addressing ----
__global__ void gat_agg4(const _Float16* __restrict__ h, const float* __restrict__ a_src,
                         const float* __restrict__ a_dst, const int* __restrict__ row_ptr,
                         const int* __restrict__ col, const float* __restrict__ bias,
                         _Float16* __restrict__ outp, int N) {
    int i = blockIdx.x;
    int w = threadIdx.x >> 6, lane = threadIdx.x & 63;
    int start = row_ptr[i], end = row_ptr[i + 1];
    int deg = end - start;

    __shared__ float invs[4];
    __shared__ float alph[4][65];          // padded: head stride 65 breaks same-bank aliasing
    __shared__ int   scol[64];
    __shared__ float accs[4][256];

    float ad = a_dst[i * 4 + w];
    if (deg <= 64) {
        float e = 0.0f; int s = 0;
        if (lane < deg) {
            s = col[start + lane];
            e = __expf(leaky(a_src[s * 4 + w] + ad));
        }
        float ssum = wave_sum(e);
        alph[w][lane] = e * (1.0f / ssum);  // premultiplied alpha
        if (w == 0) scol[lane] = s;
    } else {
        float ssum = 0.0f;
        for (int j = start + lane; j < end; j += 64)
            ssum += __expf(leaky(a_src[col[j] * 4 + w] + ad));
        ssum = wave_sum(ssum);
        if (lane == 0) invs[w] = 1.0f / ssum;
    }
    __syncthreads();

    int hh = lane >> 4;
    const _Float16* hb = h + lane * 4;     // per-lane column base (loop-invariant)
    float4 acc = make_float4(0.f, 0.f, 0.f, 0.f);
    if (deg <= 64) {
        int chunk = (deg + 3) >> 2;
        int jb = w * chunk;
        int je = min(jb + chunk, deg);
        int j = jb;
        for (; j + 1 < je; j += 2) {
            int s0 = __builtin_amdgcn_readfirstlane(scol[j]);
            int s1 = __builtin_amdgcn_readfirstlane(scol[j + 1]);
            float a0 = alph[hh][j], a1 = alph[hh][j + 1];
            half4v v0 = *(const half4v*)(hb + (size_t)s0 * 256);
            half4v v1 = *(const half4v*)(hb + (size_t)s1 * 256);
            acc.x += a0 * (float)v0[0] + a1 * (float)v1[0];
            acc.y += a0 * (float)v0[1] + a1 * (float)v1[1];
            acc.z += a0 * (float)v0[2] + a1 * (float)v1[2];
            acc.w += a0 * (float)v0[3] + a1 * (float)v1[3];
        }
        if (j < je) {
            int s0 = __builtin_amdgcn_readfirstlane(scol[j]);
            float a0 = alph[hh][j];
            half4v v0 = *(const half4v*)(hb + (size_t)s0 * 256);
            acc.x += a0 * (float)v0[0]; acc.y += a0 * (float)v0[1];
            acc.z += a0 * (float)v0[2]; acc.w += a0 * (float)v0[3];
        }
    } else {
        float ih = invs[hh];
        float adh = a_dst[i * 4 + hh];
        for (int j = start + w; j < end; j += 4) {
            int s = col[j];
            float alpha = __expf(leaky(a_src[s * 4 + hh] + adh)) * ih;
            half4v v = *(const half4v*)(h + (size_t)s * 256 + lane * 4);
            acc.x += alpha * (float)v[0]; acc.y += alpha * (float)v[1];
            acc.z += alpha * (float)v[2]; acc.w += alpha * (float)v[3];
        }
    }
    *(float4*)&accs[w][lane * 4] = acc;
    __syncthreads();

    int c = threadIdx.x;
    float sum = accs[0][c] + accs[1][c] + accs[2][c] + accs[3][c];
    outp[(size_t)i * 256 + c] = (_Float16)leaky(sum + bias[c]);
}

// ---------------- GAT aggregation, H=1: premultiplied LDS alphas + 2-deep batching -------
__global__ void gat_agg1h(const _Float16* __restrict__ h, const float* __restrict__ a_src,
                          const float* __restrict__ a_dst, const int* __restrict__ row_ptr,
                          const int* __restrict__ col, const float* __restrict__ bias,
                          float* __restrict__ outp, int N) {
    int i = blockIdx.x;
    int w = threadIdx.x >> 6, lane = threadIdx.x & 63;
    int start = row_ptr[i], end = row_ptr[i + 1];
    int deg = end - start;
    float ad = a_dst[i];

    __shared__ float alph[64];
    __shared__ float sinv[1];
    __shared__ int   scol[64];
    __shared__ float accs[4][64];

    if (deg <= 64) {
        if (w == 0) {
            int s = 0; float e = 0.0f;
            if (lane < deg) {
                s = col[start + lane];
                e = __expf(leaky(a_src[s] + ad));
            }
            float ssum = wave_sum(e);
            scol[lane] = s;
            alph[lane] = e * (1.0f / ssum);
        }
    } else {
        if (w == 0) {
            float ssum = 0.0f;
            for (int j = start + lane; j < end; j += 64)
                ssum += __expf(leaky(a_src[col[j]] + ad));
            ssum = wave_sum(ssum);
            if (lane == 0) sinv[0] = 1.0f / ssum;
        }
    }
    __syncthreads();

    int sub = lane >> 4;
    int c4 = (lane & 15) * 4;
    int es = w * 4 + sub;                  // 0..15: subgroup's edge offset
    float4 acc = make_float4(0.f, 0.f, 0.f, 0.f);
    if (deg <= 64) {
        int j = es;
        for (; j + 16 < deg; j += 32) {
            int s0 = scol[j], s1 = scol[j + 16];
            float a0 = alph[j], a1 = alph[j + 16];
            half4v v0 = *(const half4v*)(h + (size_t)s0 * 64 + c4);
            half4v v1 = *(const half4v*)(h + (size_t)s1 * 64 + c4);
            acc.x += a0 * (float)v0[0] + a1 * (float)v1[0];
            acc.y += a0 * (float)v0[1] + a1 * (float)v1[1];
            acc.z += a0 * (float)v0[2] + a1 * (float)v1[2];
            acc.w += a0 * (float)v0[3] + a1 * (float)v1[3];
        }
        for (; j < deg; j += 16) {
            int s = scol[j];
            float a0 = alph[j];
            half4v v = *(const half4v*)(h + (size_t)s * 64 + c4);
            acc.x += a0 * (float)v[0]; acc.y += a0 * (float)v[1];
            acc.z += a0 * (float)v[2]; acc.w += a0 * (float)v[3];
        }
    } else {
        float inv = sinv[0];
        for (int j = start + es; j < end; j += 16) {
            int s = col[j];
            float alpha = __expf(leaky(a_src[s] + ad)) * inv;
            half4v v = *(const half4v*)(h + (size_t)s * 64 + c4);
            acc.x += alpha * (float)v[0]; acc.y += alpha * (float)v[1];
            acc.z += alpha * (float)v[2]; acc.w += alpha * (float)v[3];
        }
    }
    #pragma unroll
    for (int o = 16; o <= 32; o <<= 1) {
        acc.x += __shfl_xor(acc.x, o, 64);
        acc.y += __shfl_xor(acc.y, o, 64);
        acc.z += __shfl_xor(acc.z, o, 64);
        acc.w += __shfl_xor(acc.w, o, 64);
    }
    if (lane < 16) *(float4*)&accs[w][c4] = acc;
    __syncthreads();
    if (threadIdx.x < 64) {
        int c = threadIdx.x;
        float sum = accs[0][c] + accs[1][c] + accs[2][c] + accs[3][c];
        outp[(size_t)i * 64 + c] = leaky(sum + bias[c]);
    }
}

// ---------------- leaky'd o2 -> LayerNorm -> + residual(lin) -> hres fp16 ----------------
__global__ void ln_res(const float* __restrict__ o2, const float* __restrict__ lin,
                       _Float16* __restrict__ hresh,
                       const float* __restrict__ gamma, const float* __restrict__ beta, int N) {
    int wave = threadIdx.x >> 6, lane = threadIdx.x & 63;
    int i = blockIdx.x * (blockDim.x >> 6) + wave;
    if (i >= N) return;
    float x = o2[(size_t)i * 64 + lane];
    float mu = wave_sum(x) * (1.0f / 64.0f);
    float d = x - mu;
    float var = wave_sum(d * d) * (1.0f / 64.0f);
    float xn = d * rsqrtf(var + LN_EPS) * gamma[lane] + beta[lane];
    float v = lin[(size_t)i * 64 + lane] + xn;
    hresh[(size_t)i * 64 + lane] = (_Float16)v;
}

// ---------------- GRU gates + FC head (gi fp16) ----------------
__global__ void gru_fc(const _Float16* __restrict__ gi, const float* __restrict__ b_hh,
                       const float* __restrict__ fc_w, const float* __restrict__ fc_b,
                       float* __restrict__ outp, int N) {
    int wave = threadIdx.x >> 6, lane = threadIdx.x & 63;
    int i = blockIdx.x * (blockDim.x >> 6) + wave;
    if (i >= N) return;
    const _Float16* g = gi + (size_t)i * 192;
    float i_r = (float)g[lane], i_z = (float)g[64 + lane], i_n = (float)g[128 + lane];
    float r = 1.0f / (1.0f + __expf(-(i_r + b_hh[lane])));
    float z = 1.0f / (1.0f + __expf(-(i_z + b_hh[64 + lane])));
    float ng = tanhf(i_n + r * b_hh[128 + lane]);
    float hy = (1.0f - z) * ng;
    #pragma unroll
    for (int k = 0; k < 3; ++k) {
        float s = wave_sum(hy * fc_w[k * 64 + lane]);
        if (lane == 0) outp[(size_t)i * 3 + k] = s + fc_b[k];
    }
}

extern "C" void kernel_launch(void* const* d_in, const int* in_sizes, int n_in,
                              void* d_out, int out_size, void* d_ws, size_t ws_size,
                              hipStream_t stream) {
    const float* x        = (const float*)d_in[0];
    const int*   ei       = (const int*)d_in[1];
    const float* W1       = (const float*)d_in[2];
    const float* att_src1 = (const float*)d_in[3];
    const float* att_dst1 = (const float*)d_in[4];
    const float* b1       = (const float*)d_in[5];
    const float* W2       = (const float*)d_in[6];
    const float* att_src2 = (const float*)d_in[7];
    const float* att_dst2 = (const float*)d_in[8];
    const float* b2       = (const float*)d_in[9];
    const float* lin_w    = (const float*)d_in[10];
    const float* lin_b    = (const float*)d_in[11];
    const float* gamma    = (const float*)d_in[12];
    const float* beta     = (const float*)d_in[13];
    const float* w_ih     = (const float*)d_in[14];
    // d_in[15] = w_hh (unused: h0 == 0)
    const float* b_ih     = (const float*)d_in[16];
    const float* b_hh     = (const float*)d_in[17];
    const float* fc_w     = (const float*)d_in[18];
    const float* fc_b     = (const float*)d_in[19];
    float* out = (float*)d_out;

    const int N = N_NODES, E = N_EDGES;
    const int Etot = E + N;
    const int nb = (N + 255) / 256;       // 196 scan blocks
    char* ws = (char*)d_ws;

    size_t off = 0;
    auto alloc = [&](size_t bytes) {
        size_t o = off;
        off = (off + bytes + 255) & ~(size_t)255;
        return o;
    };
    int*      row_ptr = (int*)(ws + alloc((size_t)(N + 1) * 4));
    int*      col     = (int*)(ws + alloc((size_t)Etot * 4));
    int*      deg     = (int*)(ws + alloc((size_t)N * 4));
    int*      fill    = (int*)(ws + alloc((size_t)N * 4));
    int*      bsum    = (int*)(ws + alloc((size_t)nb * 4));
    float*    a_src1b = (float*)(ws + alloc((size_t)N * HEADS * 4));
    float*    a_dst1b = (float*)(ws + alloc((size_t)N * HEADS * 4));
    float*    a_src2b = (float*)(ws + alloc((size_t)N * 4));
    float*    a_dst2b = (float*)(ws + alloc((size_t)N * 4));
    _Float16* W1h     = (_Float16*)(ws + alloc((size_t)256 * 256 * 2));
    _Float16* W2h     = (_Float16*)(ws + alloc((size_t)64 * 256 * 2));
    _Float16* lin_wh  = (_Float16*)(ws + alloc((size_t)64 * 256 * 2));
    _Float16* w_ihh   = (_Float16*)(ws + alloc((size_t)192 * 64 * 2));
    // big region (64MB): xh@0 (25.6M), h1h@25.6M (25.6M), lin@51.2M (12.8M).
    // gi (fp16, 19.2M) aliases [0, 19.2M) AFTER xh is dead; h1h/lin untouched.
    char* big = ws + alloc((size_t)64000000);
    _Float16* xh   = (_Float16*)big;
    _Float16* h1h  = (_Float16*)(big + 25600000);
    float*    lin  = (float*)(big + 51200000);
    _Float16* gi   = (_Float16*)big;
    // region r3 (25.6M): o1h (fp16 [N,256]); after gemm2 consumes it, reused as o2 (fp32 [N,64])
    char* r3 = ws + alloc((size_t)25600000);
    _Float16* o1h = (_Float16*)r3;
    float*    o2  = (float*)r3;
    // region r4 (6.4M): h2h (fp16 [N,64]); after gat_agg1h, reused as hresh (fp16 [N,64])
    char* r4 = ws + alloc((size_t)6400000);
    _Float16* h2h   = (_Float16*)r4;
    _Float16* hresh = (_Float16*)r4;

    hipMemsetAsync(deg, 0, (size_t)N * 4, stream);
    hipMemsetAsync(fill, 0, (size_t)N * 4, stream);

    // ---- CSR build ----
    count_kernel<<<(Etot + 255) / 256, 256, 0, stream>>>(ei + E, deg, E, Etot);
    scan_part<<<nb, 256, 0, stream>>>(deg, bsum, N);
    scan_top<<<1, 256, 0, stream>>>(bsum, nb);
    scan_final<<<nb, 256, 0, stream>>>(deg, bsum, row_ptr, N);
    scatter_kernel<<<(Etot + 255) / 256, 256, 0, stream>>>(ei, ei + E, row_ptr, fill, col, E, Etot);

    // ---- fp16 conversions (one kernel, 5 ranges) ----
    {
        CvtJob j0{x, xh, N * F_IN};
        CvtJob j1{W1, W1h, 256 * 256};
        CvtJob j2{W2, W2h, 64 * 256};
        CvtJob j3{lin_w, lin_wh, 64 * 256};
        CvtJob j4{w_ih, w_ihh, 192 * 64};
        int total4 = (j0.len + j1.len + j2.len + j3.len + j4.len) / 4;
        cvt_f16_multi<<<(total4 + 255) / 256, 256, 0, stream>>>(j0, j1, j2, j3, j4);
    }

    const int gmBlocks = (N + 63) / 64;   // 782

    // ---- GAT layer 1 GEMM + att coefs + lin projection, all fused ----
    gemm1_fused<<<gmBlocks, 256, 0, stream>>>(xh, W1h, lin_wh, lin_b, h1h, lin,
        att_src1, att_dst1, a_src1b, a_dst1b, N);
    gat_agg4<<<N, 256, 0, stream>>>(h1h, a_src1b, a_dst1b, row_ptr, col, b1, o1h, N);

    // ---- GAT layer 2 (att coefs fused) ----
    gemm_mfma<4, 1, _Float16><<<gmBlocks, 256, 0, stream>>>(o1h, W2h, nullptr, h2h,
        att_src2, att_dst2, a_src2b, a_dst2b, N, 256, 0);
    gat_agg1h<<<N, 256, 0, stream>>>(h2h, a_src2b, a_dst2b, row_ptr, col, b2, o2, N);

    // ---- LayerNorm + residual -> hres fp16 ----
    ln_res<<<(N + 3) / 4, 256, 0, stream>>>(o2, lin, hresh, gamma, beta, N);

    // ---- GRU input GEMM: gi = hres @ w_ih^T + b_ih (fp16 out) ----
    gemm_mfma<12, 0, _Float16><<<gmBlocks, 256, 0, stream>>>(hresh, w_ihh, b_ih, gi,
        nullptr, nullptr, nullptr, nullptr, N, 64, 1);

    // ---- GRU gates + FC head ----
    gru_fc<<<(N + 3) / 4, 256, 0, stream>>>(gi, b_hh, fc_w, fc_b, out, N);
}

// Round 9
// 518.070 us; speedup vs baseline: 1.0665x; 1.0665x over previous
//
#include <hip/hip_runtime.h>
#include <hip/hip_bf16.h>

#define N_NODES 50000
#define N_EDGES 800000
#define F_IN 256
#define HID 64
#define HEADS 4
#define NEG 0.2f
#define LN_EPS 1e-5f

typedef _Float16 half8 __attribute__((ext_vector_type(8)));
typedef _Float16 half4v __attribute__((ext_vector_type(4)));
typedef float floatx4 __attribute__((ext_vector_type(4)));

__device__ __forceinline__ float wave_sum(float v) {
    #pragma unroll
    for (int o = 32; o > 0; o >>= 1) v += __shfl_xor(v, o, 64);
    return v;
}
__device__ __forceinline__ int wave_sum_i(int v) {
    #pragma unroll
    for (int o = 32; o > 0; o >>= 1) v += __shfl_xor(v, o, 64);
    return v;
}
__device__ __forceinline__ float leaky(float x) { return x > 0.0f ? x : NEG * x; }

// ---------------- CSR build ----------------
__global__ void count_kernel(const int* __restrict__ dst, int* __restrict__ deg,
                             int E, int Etot) {
    int e = blockIdx.x * blockDim.x + threadIdx.x;
    if (e >= Etot) return;
    int d = (e < E) ? dst[e] : (e - E);   // tail = self loops
    atomicAdd(&deg[d], 1);
}

__global__ void scan_part(const int* __restrict__ deg, int* __restrict__ bsum, int N) {
    int tid = threadIdx.x;
    int i = blockIdx.x * 256 + tid;
    int v = (i < N) ? deg[i] : 0;
    int s = wave_sum_i(v);
    __shared__ int ws4[4];
    if ((tid & 63) == 0) ws4[tid >> 6] = s;
    __syncthreads();
    if (tid == 0) bsum[blockIdx.x] = ws4[0] + ws4[1] + ws4[2] + ws4[3];
}

__global__ void scan_top(int* __restrict__ bsum, int nb) {   // in-place exclusive
    __shared__ int sh[256];
    int t = threadIdx.x;
    int v = (t < nb) ? bsum[t] : 0;
    sh[t] = v;
    __syncthreads();
    for (int o = 1; o < 256; o <<= 1) {
        int u = (t >= o) ? sh[t - o] : 0;
        __syncthreads();
        sh[t] += u;
        __syncthreads();
    }
    if (t < nb) bsum[t] = sh[t] - v;    // exclusive
}

__global__ void scan_final(const int* __restrict__ deg, const int* __restrict__ bsum,
                           int* __restrict__ row_ptr, int N) {
    __shared__ int sh[256];
    int t = threadIdx.x;
    int i = blockIdx.x * 256 + t;
    int v = (i < N) ? deg[i] : 0;
    sh[t] = v;
    __syncthreads();
    for (int o = 1; o < 256; o <<= 1) {
        int u = (t >= o) ? sh[t - o] : 0;
        __syncthreads();
        sh[t] += u;
        __syncthreads();
    }
    if (i < N) row_ptr[i + 1] = bsum[blockIdx.x] + sh[t];   // inclusive prefix
    if (i == 0) row_ptr[0] = 0;
}

__global__ void scatter_kernel(const int* __restrict__ src, const int* __restrict__ dst,
                               const int* __restrict__ row_ptr, int* __restrict__ fill,
                               int* __restrict__ col, int E, int Etot) {
    int e = blockIdx.x * blockDim.x + threadIdx.x;
    if (e >= Etot) return;
    int s, d;
    if (e < E) { s = src[e]; d = dst[e]; }
    else       { s = d = e - E; }
    int pos = atomicAdd(&fill[d], 1);
    col[row_ptr[d] + pos] = s;
}

// ---------------- merged fp32 -> fp16 conversion over 5 ranges ----------------
struct CvtJob { const float* src; _Float16* dst; int len; };
__global__ void cvt_f16_multi(CvtJob j0, CvtJob j1, CvtJob j2, CvtJob j3, CvtJob j4) {
    int idx = (blockIdx.x * blockDim.x + threadIdx.x) * 4;
    const float* s; _Float16* d; int rel = idx;
    if      (rel < j0.len) { s = j0.src; d = j0.dst; }
    else if ((rel -= j0.len) < j1.len) { s = j1.src; d = j1.dst; }
    else if ((rel -= j1.len) < j2.len) { s = j2.src; d = j2.dst; }
    else if ((rel -= j2.len) < j3.len) { s = j3.src; d = j3.dst; }
    else if ((rel -= j3.len) < j4.len) { s = j4.src; d = j4.dst; }
    else return;
    float4 v = *(const float4*)(s + rel);
    half4v h;
    h[0] = (_Float16)v.x; h[1] = (_Float16)v.y;
    h[2] = (_Float16)v.z; h[3] = (_Float16)v.w;
    *(half4v*)(d + rel) = h;
}

// ---------------- generic fp16 MFMA GEMM + optional att epilogue (LDS-staged stores) -----
// NT<=16 keeps accumulator pressure at <=64 VGPRs (NT=20 in R7/R8 spilled in the K-loop:
// ~230MB of scratch traffic, 97% stall — do NOT fuse extra tiles into one kernel).
template<int NT, int H, typename OutT>
__global__ void gemm_mfma(const _Float16* __restrict__ A, const _Float16* __restrict__ B,
                          const float* __restrict__ bias, OutT* __restrict__ Cout,
                          const float* __restrict__ att_s, const float* __restrict__ att_d,
                          float* __restrict__ a_srcO, float* __restrict__ a_dstO,
                          int M, int K, int add_bias) {
    constexpr int TILEB = 16 * NT * 16 * sizeof(OutT);   // per-wave staged bytes
    __shared__ __align__(16) char smem[4 * TILEB];
    int w = threadIdx.x >> 6, lane = threadIdx.x & 63;
    int m_base = blockIdx.x * 64 + w * 16;
    if (m_base >= M) return;
    int r = lane & 15, q = lane >> 4;
    const _Float16* ap = A + (size_t)(m_base + r) * K + q * 8;
    const _Float16* bp = B + (size_t)r * K + q * 8;
    floatx4 acc[NT];
    #pragma unroll
    for (int t = 0; t < NT; ++t) acc[t] = (floatx4){0.f, 0.f, 0.f, 0.f};
    for (int k0 = 0; k0 < K; k0 += 32) {
        half8 a = *(const half8*)(ap + k0);
        #pragma unroll
        for (int t = 0; t < NT; ++t) {
            half8 b = *(const half8*)(bp + (size_t)t * 16 * K + k0);
            acc[t] = __builtin_amdgcn_mfma_f32_16x16x32_f16(a, b, acc[t], 0, 0, 0);
        }
    }
    const int Nc = NT * 16;
    OutT* st = (OutT*)(smem + w * TILEB);
    #pragma unroll
    for (int t = 0; t < NT; ++t) {
        int cc = t * 16 + r;
        float bv = add_bias ? bias[cc] : 0.0f;
        #pragma unroll
        for (int rr = 0; rr < 4; ++rr)
            st[(q * 4 + rr) * Nc + cc] = (OutT)(acc[t][rr] + bv);
    }
    {
        constexpr int NISS = TILEB / 1024;               // 1KB coalesced issues
        const int4* src = (const int4*)st;
        int4* dst = (int4*)((char*)Cout + (size_t)m_base * (Nc * sizeof(OutT)));
        #pragma unroll
        for (int i = 0; i < NISS; ++i) dst[i * 64 + lane] = src[i * 64 + lane];
    }
    if constexpr (H > 0) {
        float ps[H][4], pd[H][4];
        #pragma unroll
        for (int h = 0; h < H; ++h) {
            #pragma unroll
            for (int rr = 0; rr < 4; ++rr) { ps[h][rr] = 0.f; pd[h][rr] = 0.f; }
            #pragma unroll
            for (int tt = 0; tt < 4; ++tt) {
                int t = h * 4 + tt;
                float as = att_s[t * 16 + r];
                float ad = att_d[t * 16 + r];
                #pragma unroll
                for (int rr = 0; rr < 4; ++rr) {
                    ps[h][rr] += acc[t][rr] * as;
                    pd[h][rr] += acc[t][rr] * ad;
                }
            }
        }
        #pragma unroll
        for (int m = 1; m < 16; m <<= 1) {
            #pragma unroll
            for (int h = 0; h < H; ++h)
                #pragma unroll
                for (int rr = 0; rr < 4; ++rr) {
                    ps[h][rr] += __shfl_xor(ps[h][rr], m, 64);
                    pd[h][rr] += __shfl_xor(pd[h][rr], m, 64);
                }
        }
        if (r == 0) {
            #pragma unroll
            for (int rr = 0; rr < 4; ++rr) {
                int gm = m_base + q * 4 + rr;
                #pragma unroll
                for (int h = 0; h < H; ++h) {
                    a_srcO[gm * H + h] = ps[h][rr];
                    a_dstO[gm * H + h] = pd[h][rr];
                }
            }
        }
    }
}

// ---------------- GAT aggregation, H=4: premultiplied LDS alphas, scalar row addressing ----
__global__ void gat_agg4(const _Float16* __restrict__ h, const float* __restrict__ a_src,
                         const float* __restrict__ a_dst, const int* __restrict__ row_ptr,
                         const int* __restrict__ col, const float* __restrict__ bias,
                         _Float16* __restrict__ outp, int N) {
    int i = blockIdx.x;
    int w = threadIdx.x >> 6, lane = threadIdx.x & 63;
    int start = row_ptr[i], end = row_ptr[i + 1];
    int deg = end - start;

    __shared__ float invs[4];
    __shared__ float alph[4][65];          // padded: head stride 65 breaks same-bank aliasing
    __shared__ int   scol[64];
    __shared__ float accs[4][256];

    float ad = a_dst[i * 4 + w];
    if (deg <= 64) {
        float e = 0.0f; int s = 0;
        if (lane < deg) {
            s = col[start + lane];
            e = __expf(leaky(a_src[s * 4 + w] + ad));
        }
        float ssum = wave_sum(e);
        alph[w][lane] = e * (1.0f / ssum);  // premultiplied alpha
        if (w == 0) scol[lane] = s;
    } else {
        float ssum = 0.0f;
        for (int j = start + lane; j < end; j += 64)
            ssum += __expf(leaky(a_src[col[j] * 4 + w] + ad));
        ssum = wave_sum(ssum);
        if (lane == 0) invs[w] = 1.0f / ssum;
    }
    __syncthreads();

    int hh = lane >> 4;
    const _Float16* hb = h + lane * 4;     // per-lane column base (loop-invariant)
    float4 acc = make_float4(0.f, 0.f, 0.f, 0.f);
    if (deg <= 64) {
        int chunk = (deg + 3) >> 2;
        int jb = w * chunk;
        int je = min(jb + chunk, deg);
        int j = jb;
        for (; j + 1 < je; j += 2) {
            int s0 = __builtin_amdgcn_readfirstlane(scol[j]);
            int s1 = __builtin_amdgcn_readfirstlane(scol[j + 1]);
            float a0 = alph[hh][j], a1 = alph[hh][j + 1];
            half4v v0 = *(const half4v*)(hb + (size_t)s0 * 256);
            half4v v1 = *(const half4v*)(hb + (size_t)s1 * 256);
            acc.x += a0 * (float)v0[0] + a1 * (float)v1[0];
            acc.y += a0 * (float)v0[1] + a1 * (float)v1[1];
            acc.z += a0 * (float)v0[2] + a1 * (float)v1[2];
            acc.w += a0 * (float)v0[3] + a1 * (float)v1[3];
        }
        if (j < je) {
            int s0 = __builtin_amdgcn_readfirstlane(scol[j]);
            float a0 = alph[hh][j];
            half4v v0 = *(const half4v*)(hb + (size_t)s0 * 256);
            acc.x += a0 * (float)v0[0]; acc.y += a0 * (float)v0[1];
            acc.z += a0 * (float)v0[2]; acc.w += a0 * (float)v0[3];
        }
    } else {
        float ih = invs[hh];
        float adh = a_dst[i * 4 + hh];
        for (int j = start + w; j < end; j += 4) {
            int s = col[j];
            float alpha = __expf(leaky(a_src[s * 4 + hh] + adh)) * ih;
            half4v v = *(const half4v*)(h + (size_t)s * 256 + lane * 4);
            acc.x += alpha * (float)v[0]; acc.y += alpha * (float)v[1];
            acc.z += alpha * (float)v[2]; acc.w += alpha * (float)v[3];
        }
    }
    *(float4*)&accs[w][lane * 4] = acc;
    __syncthreads();

    int c = threadIdx.x;
    float sum = accs[0][c] + accs[1][c] + accs[2][c] + accs[3][c];
    outp[(size_t)i * 256 + c] = (_Float16)leaky(sum + bias[c]);
}

// ---------------- GAT aggregation, H=1: premultiplied LDS alphas + 2-deep batching -------
__global__ void gat_agg1h(const _Float16* __restrict__ h, const float* __restrict__ a_src,
                          const float* __restrict__ a_dst, const int* __restrict__ row_ptr,
                          const int* __restrict__ col, const float* __restrict__ bias,
                          float* __restrict__ outp, int N) {
    int i = blockIdx.x;
    int w = threadIdx.x >> 6, lane = threadIdx.x & 63;
    int start = row_ptr[i], end = row_ptr[i + 1];
    int deg = end - start;
    float ad = a_dst[i];

    __shared__ float alph[64];
    __shared__ float sinv[1];
    __shared__ int   scol[64];
    __shared__ float accs[4][64];

    if (deg <= 64) {
        if (w == 0) {
            int s = 0; float e = 0.0f;
            if (lane < deg) {
                s = col[start + lane];
                e = __expf(leaky(a_src[s] + ad));
            }
            float ssum = wave_sum(e);
            scol[lane] = s;
            alph[lane] = e * (1.0f / ssum);
        }
    } else {
        if (w == 0) {
            float ssum = 0.0f;
            for (int j = start + lane; j < end; j += 64)
                ssum += __expf(leaky(a_src[col[j]] + ad));
            ssum = wave_sum(ssum);
            if (lane == 0) sinv[0] = 1.0f / ssum;
        }
    }
    __syncthreads();

    int sub = lane >> 4;
    int c4 = (lane & 15) * 4;
    int es = w * 4 + sub;                  // 0..15: subgroup's edge offset
    float4 acc = make_float4(0.f, 0.f, 0.f, 0.f);
    if (deg <= 64) {
        int j = es;
        for (; j + 16 < deg; j += 32) {
            int s0 = scol[j], s1 = scol[j + 16];
            float a0 = alph[j], a1 = alph[j + 16];
            half4v v0 = *(const half4v*)(h + (size_t)s0 * 64 + c4);
            half4v v1 = *(const half4v*)(h + (size_t)s1 * 64 + c4);
            acc.x += a0 * (float)v0[0] + a1 * (float)v1[0];
            acc.y += a0 * (float)v0[1] + a1 * (float)v1[1];
            acc.z += a0 * (float)v0[2] + a1 * (float)v1[2];
            acc.w += a0 * (float)v0[3] + a1 * (float)v1[3];
        }
        for (; j < deg; j += 16) {
            int s = scol[j];
            float a0 = alph[j];
            half4v v = *(const half4v*)(h + (size_t)s * 64 + c4);
            acc.x += a0 * (float)v[0]; acc.y += a0 * (float)v[1];
            acc.z += a0 * (float)v[2]; acc.w += a0 * (float)v[3];
        }
    } else {
        float inv = sinv[0];
        for (int j = start + es; j < end; j += 16) {
            int s = col[j];
            float alpha = __expf(leaky(a_src[s] + ad)) * inv;
            half4v v = *(const half4v*)(h + (size_t)s * 64 + c4);
            acc.x += alpha * (float)v[0]; acc.y += alpha * (float)v[1];
            acc.z += alpha * (float)v[2]; acc.w += alpha * (float)v[3];
        }
    }
    #pragma unroll
    for (int o = 16; o <= 32; o <<= 1) {
        acc.x += __shfl_xor(acc.x, o, 64);
        acc.y += __shfl_xor(acc.y, o, 64);
        acc.z += __shfl_xor(acc.z, o, 64);
        acc.w += __shfl_xor(acc.w, o, 64);
    }
    if (lane < 16) *(float4*)&accs[w][c4] = acc;
    __syncthreads();
    if (threadIdx.x < 64) {
        int c = threadIdx.x;
        float sum = accs[0][c] + accs[1][c] + accs[2][c] + accs[3][c];
        outp[(size_t)i * 64 + c] = leaky(sum + bias[c]);
    }
}

// ---------------- leaky'd o2 -> LayerNorm -> + residual(lin) -> hres fp16 ----------------
__global__ void ln_res(const float* __restrict__ o2, const float* __restrict__ lin,
                       _Float16* __restrict__ hresh,
                       const float* __restrict__ gamma, const float* __restrict__ beta, int N) {
    int wave = threadIdx.x >> 6, lane = threadIdx.x & 63;
    int i = blockIdx.x * (blockDim.x >> 6) + wave;
    if (i >= N) return;
    float x = o2[(size_t)i * 64 + lane];
    float mu = wave_sum(x) * (1.0f / 64.0f);
    float d = x - mu;
    float var = wave_sum(d * d) * (1.0f / 64.0f);
    float xn = d * rsqrtf(var + LN_EPS) * gamma[lane] + beta[lane];
    float v = lin[(size_t)i * 64 + lane] + xn;
    hresh[(size_t)i * 64 + lane] = (_Float16)v;
}

// ---------------- GRU gates + FC head (gi fp16) ----------------
__global__ void gru_fc(const _Float16* __restrict__ gi, const float* __restrict__ b_hh,
                       const float* __restrict__ fc_w, const float* __restrict__ fc_b,
                       float* __restrict__ outp, int N) {
    int wave = threadIdx.x >> 6, lane = threadIdx.x & 63;
    int i = blockIdx.x * (blockDim.x >> 6) + wave;
    if (i >= N) return;
    const _Float16* g = gi + (size_t)i * 192;
    float i_r = (float)g[lane], i_z = (float)g[64 + lane], i_n = (float)g[128 + lane];
    float r = 1.0f / (1.0f + __expf(-(i_r + b_hh[lane])));
    float z = 1.0f / (1.0f + __expf(-(i_z + b_hh[64 + lane])));
    float ng = tanhf(i_n + r * b_hh[128 + lane]);
    float hy = (1.0f - z) * ng;
    #pragma unroll
    for (int k = 0; k < 3; ++k) {
        float s = wave_sum(hy * fc_w[k * 64 + lane]);
        if (lane == 0) outp[(size_t)i * 3 + k] = s + fc_b[k];
    }
}

extern "C" void kernel_launch(void* const* d_in, const int* in_sizes, int n_in,
                              void* d_out, int out_size, void* d_ws, size_t ws_size,
                              hipStream_t stream) {
    const float* x        = (const float*)d_in[0];
    const int*   ei       = (const int*)d_in[1];
    const float* W1       = (const float*)d_in[2];
    const float* att_src1 = (const float*)d_in[3];
    const float* att_dst1 = (const float*)d_in[4];
    const float* b1       = (const float*)d_in[5];
    const float* W2       = (const float*)d_in[6];
    const float* att_src2 = (const float*)d_in[7];
    const float* att_dst2 = (const float*)d_in[8];
    const float* b2       = (const float*)d_in[9];
    const float* lin_w    = (const float*)d_in[10];
    const float* lin_b    = (const float*)d_in[11];
    const float* gamma    = (const float*)d_in[12];
    const float* beta     = (const float*)d_in[13];
    const float* w_ih     = (const float*)d_in[14];
    // d_in[15] = w_hh (unused: h0 == 0)
    const float* b_ih     = (const float*)d_in[16];
    const float* b_hh     = (const float*)d_in[17];
    const float* fc_w     = (const float*)d_in[18];
    const float* fc_b     = (const float*)d_in[19];
    float* out = (float*)d_out;

    const int N = N_NODES, E = N_EDGES;
    const int Etot = E + N;
    const int nb = (N + 255) / 256;       // 196 scan blocks
    char* ws = (char*)d_ws;

    size_t off = 0;
    auto alloc = [&](size_t bytes) {
        size_t o = off;
        off = (off + bytes + 255) & ~(size_t)255;
        return o;
    };
    int*      row_ptr = (int*)(ws + alloc((size_t)(N + 1) * 4));
    int*      col     = (int*)(ws + alloc((size_t)Etot * 4));
    int*      deg     = (int*)(ws + alloc((size_t)N * 4));
    int*      fill    = (int*)(ws + alloc((size_t)N * 4));
    int*      bsum    = (int*)(ws + alloc((size_t)nb * 4));
    float*    a_src1b = (float*)(ws + alloc((size_t)N * HEADS * 4));
    float*    a_dst1b = (float*)(ws + alloc((size_t)N * HEADS * 4));
    float*    a_src2b = (float*)(ws + alloc((size_t)N * 4));
    float*    a_dst2b = (float*)(ws + alloc((size_t)N * 4));
    _Float16* W1h     = (_Float16*)(ws + alloc((size_t)256 * 256 * 2));
    _Float16* W2h     = (_Float16*)(ws + alloc((size_t)64 * 256 * 2));
    _Float16* lin_wh  = (_Float16*)(ws + alloc((size_t)64 * 256 * 2));
    _Float16* w_ihh   = (_Float16*)(ws + alloc((size_t)192 * 64 * 2));
    // big region (64MB): xh@0 (25.6M), h1h@25.6M (25.6M), lin@51.2M (12.8M).
    // gi (fp16, 19.2M) aliases [0, 19.2M) AFTER xh is dead; h1h/lin untouched.
    char* big = ws + alloc((size_t)64000000);
    _Float16* xh   = (_Float16*)big;
    _Float16* h1h  = (_Float16*)(big + 25600000);
    float*    lin  = (float*)(big + 51200000);
    _Float16* gi   = (_Float16*)big;
    // region r3 (25.6M): o1h (fp16 [N,256]); after gemm2 consumes it, reused as o2 (fp32 [N,64])
    char* r3 = ws + alloc((size_t)25600000);
    _Float16* o1h = (_Float16*)r3;
    float*    o2  = (float*)r3;
    // region r4 (6.4M): h2h (fp16 [N,64]); after gat_agg1h, reused as hresh (fp16 [N,64])
    char* r4 = ws + alloc((size_t)6400000);
    _Float16* h2h   = (_Float16*)r4;
    _Float16* hresh = (_Float16*)r4;

    hipMemsetAsync(deg, 0, (size_t)N * 4, stream);
    hipMemsetAsync(fill, 0, (size_t)N * 4, stream);

    // ---- CSR build ----
    count_kernel<<<(Etot + 255) / 256, 256, 0, stream>>>(ei + E, deg, E, Etot);
    scan_part<<<nb, 256, 0, stream>>>(deg, bsum, N);
    scan_top<<<1, 256, 0, stream>>>(bsum, nb);
    scan_final<<<nb, 256, 0, stream>>>(deg, bsum, row_ptr, N);
    scatter_kernel<<<(Etot + 255) / 256, 256, 0, stream>>>(ei, ei + E, row_ptr, fill, col, E, Etot);

    // ---- fp16 conversions (one kernel, 5 ranges) ----
    {
        CvtJob j0{x, xh, N * F_IN};
        CvtJob j1{W1, W1h, 256 * 256};
        CvtJob j2{W2, W2h, 64 * 256};
        CvtJob j3{lin_w, lin_wh, 64 * 256};
        CvtJob j4{w_ih, w_ihh, 192 * 64};
        int total4 = (j0.len + j1.len + j2.len + j3.len + j4.len) / 4;
        cvt_f16_multi<<<(total4 + 255) / 256, 256, 0, stream>>>(j0, j1, j2, j3, j4);
    }

    const int gmBlocks = (N + 63) / 64;   // 782

    // ---- GAT layer 1 GEMM (+att coefs) — UNFUSED from lin (NT=20 spilled; NT=16 fits) ----
    gemm_mfma<16, 4, _Float16><<<gmBlocks, 256, 0, stream>>>(xh, W1h, nullptr, h1h,
        att_src1, att_dst1, a_src1b, a_dst1b, N, 256, 0);
    gat_agg4<<<N, 256, 0, stream>>>(h1h, a_src1b, a_dst1b, row_ptr, col, b1, o1h, N);

    // ---- residual projection: lin = x @ lin_w^T + lin_b (fp32 out) ----
    gemm_mfma<4, 0, float><<<gmBlocks, 256, 0, stream>>>(xh, lin_wh, lin_b, lin,
        nullptr, nullptr, nullptr, nullptr, N, 256, 1);

    // ---- GAT layer 2 (att coefs fused) ----
    gemm_mfma<4, 1, _Float16><<<gmBlocks, 256, 0, stream>>>(o1h, W2h, nullptr, h2h,
        att_src2, att_dst2, a_src2b, a_dst2b, N, 256, 0);
    gat_agg1h<<<N, 256, 0, stream>>>(h2h, a_src2b, a_dst2b, row_ptr, col, b2, o2, N);

    // ---- LayerNorm + residual -> hres fp16 ----
    ln_res<<<(N + 3) / 4, 256, 0, stream>>>(o2, lin, hresh, gamma, beta, N);

    // ---- GRU input GEMM: gi = hres @ w_ih^T + b_ih (fp16 out) ----
    gemm_mfma<12, 0, _Float16><<<gmBlocks, 256, 0, stream>>>(hresh, w_ihh, b_ih, gi,
        nullptr, nullptr, nullptr, nullptr, N, 64, 1);

    // ---- GRU gates + FC head ----
    gru_fc<<<(N + 3) / 4, 256, 0, stream>>>(gi, b_hh, fc_w, fc_b, out, N);
}

// Round 10
// 444.072 us; speedup vs baseline: 1.2442x; 1.1666x over previous
//
#include <hip/hip_runtime.h>
#include <hip/hip_bf16.h>

#define N_NODES 50000
#define N_EDGES 800000
#define F_IN 256
#define HID 64
#define HEADS 4
#define NEG 0.2f
#define LN_EPS 1e-5f

typedef _Float16 half8 __attribute__((ext_vector_type(8)));
typedef _Float16 half4v __attribute__((ext_vector_type(4)));
typedef float floatx4 __attribute__((ext_vector_type(4)));

__device__ __forceinline__ float wave_sum(float v) {
    #pragma unroll
    for (int o = 32; o > 0; o >>= 1) v += __shfl_xor(v, o, 64);
    return v;
}
__device__ __forceinline__ int wave_sum_i(int v) {
    #pragma unroll
    for (int o = 32; o > 0; o >>= 1) v += __shfl_xor(v, o, 64);
    return v;
}
__device__ __forceinline__ float leaky(float x) { return x > 0.0f ? x : NEG * x; }

// ---------------- CSR build ----------------
__global__ void count_kernel(const int* __restrict__ dst, int* __restrict__ deg,
                             int E, int Etot) {
    int e = blockIdx.x * blockDim.x + threadIdx.x;
    if (e >= Etot) return;
    int d = (e < E) ? dst[e] : (e - E);   // tail = self loops
    atomicAdd(&deg[d], 1);
}

__global__ void scan_part(const int* __restrict__ deg, int* __restrict__ bsum, int N) {
    int tid = threadIdx.x;
    int i = blockIdx.x * 256 + tid;
    int v = (i < N) ? deg[i] : 0;
    int s = wave_sum_i(v);
    __shared__ int ws4[4];
    if ((tid & 63) == 0) ws4[tid >> 6] = s;
    __syncthreads();
    if (tid == 0) bsum[blockIdx.x] = ws4[0] + ws4[1] + ws4[2] + ws4[3];
}

__global__ void scan_top(int* __restrict__ bsum, int nb) {   // in-place exclusive
    __shared__ int sh[256];
    int t = threadIdx.x;
    int v = (t < nb) ? bsum[t] : 0;
    sh[t] = v;
    __syncthreads();
    for (int o = 1; o < 256; o <<= 1) {
        int u = (t >= o) ? sh[t - o] : 0;
        __syncthreads();
        sh[t] += u;
        __syncthreads();
    }
    if (t < nb) bsum[t] = sh[t] - v;    // exclusive
}

__global__ void scan_final(const int* __restrict__ deg, const int* __restrict__ bsum,
                           int* __restrict__ row_ptr, int N) {
    __shared__ int sh[256];
    int t = threadIdx.x;
    int i = blockIdx.x * 256 + t;
    int v = (i < N) ? deg[i] : 0;
    sh[t] = v;
    __syncthreads();
    for (int o = 1; o < 256; o <<= 1) {
        int u = (t >= o) ? sh[t - o] : 0;
        __syncthreads();
        sh[t] += u;
        __syncthreads();
    }
    if (i < N) row_ptr[i + 1] = bsum[blockIdx.x] + sh[t];   // inclusive prefix
    if (i == 0) row_ptr[0] = 0;
}

__global__ void scatter_kernel(const int* __restrict__ src, const int* __restrict__ dst,
                               const int* __restrict__ row_ptr, int* __restrict__ fill,
                               int* __restrict__ col, int E, int Etot) {
    int e = blockIdx.x * blockDim.x + threadIdx.x;
    if (e >= Etot) return;
    int s, d;
    if (e < E) { s = src[e]; d = dst[e]; }
    else       { s = d = e - E; }
    int pos = atomicAdd(&fill[d], 1);
    col[row_ptr[d] + pos] = s;
}

// ---------------- merged fp32 -> fp16 conversion over 5 ranges ----------------
struct CvtJob { const float* src; _Float16* dst; int len; };
__global__ void cvt_f16_multi(CvtJob j0, CvtJob j1, CvtJob j2, CvtJob j3, CvtJob j4) {
    int idx = (blockIdx.x * blockDim.x + threadIdx.x) * 4;
    const float* s; _Float16* d; int rel = idx;
    if      (rel < j0.len) { s = j0.src; d = j0.dst; }
    else if ((rel -= j0.len) < j1.len) { s = j1.src; d = j1.dst; }
    else if ((rel -= j1.len) < j2.len) { s = j2.src; d = j2.dst; }
    else if ((rel -= j2.len) < j3.len) { s = j3.src; d = j3.dst; }
    else if ((rel -= j3.len) < j4.len) { s = j4.src; d = j4.dst; }
    else return;
    float4 v = *(const float4*)(s + rel);
    half4v h;
    h[0] = (_Float16)v.x; h[1] = (_Float16)v.y;
    h[2] = (_Float16)v.z; h[3] = (_Float16)v.w;
    *(half4v*)(d + rel) = h;
}

// ---------------- generic fp16 MFMA GEMM + optional att epilogue (LDS-staged stores) -----
// NT<=16: accumulator pressure <=64 VGPRs (NT=20 spilled: ~230MB scratch traffic — R7/R8).
template<int NT, int H, typename OutT>
__global__ void gemm_mfma(const _Float16* __restrict__ A, const _Float16* __restrict__ B,
                          const float* __restrict__ bias, OutT* __restrict__ Cout,
                          const float* __restrict__ att_s, const float* __restrict__ att_d,
                          float* __restrict__ a_srcO, float* __restrict__ a_dstO,
                          int M, int K, int add_bias) {
    constexpr int TILEB = 16 * NT * 16 * sizeof(OutT);   // per-wave staged bytes
    __shared__ __align__(16) char smem[4 * TILEB];
    int w = threadIdx.x >> 6, lane = threadIdx.x & 63;
    int m_base = blockIdx.x * 64 + w * 16;
    if (m_base >= M) return;
    int r = lane & 15, q = lane >> 4;
    const _Float16* ap = A + (size_t)(m_base + r) * K + q * 8;
    const _Float16* bp = B + (size_t)r * K + q * 8;
    floatx4 acc[NT];
    #pragma unroll
    for (int t = 0; t < NT; ++t) acc[t] = (floatx4){0.f, 0.f, 0.f, 0.f};
    for (int k0 = 0; k0 < K; k0 += 32) {
        half8 a = *(const half8*)(ap + k0);
        #pragma unroll
        for (int t = 0; t < NT; ++t) {
            half8 b = *(const half8*)(bp + (size_t)t * 16 * K + k0);
            acc[t] = __builtin_amdgcn_mfma_f32_16x16x32_f16(a, b, acc[t], 0, 0, 0);
        }
    }
    const int Nc = NT * 16;
    OutT* st = (OutT*)(smem + w * TILEB);
    #pragma unroll
    for (int t = 0; t < NT; ++t) {
        int cc = t * 16 + r;
        float bv = add_bias ? bias[cc] : 0.0f;
        #pragma unroll
        for (int rr = 0; rr < 4; ++rr)
            st[(q * 4 + rr) * Nc + cc] = (OutT)(acc[t][rr] + bv);
    }
    {
        constexpr int NISS = TILEB / 1024;               // 1KB coalesced issues
        const int4* src = (const int4*)st;
        int4* dst = (int4*)((char*)Cout + (size_t)m_base * (Nc * sizeof(OutT)));
        #pragma unroll
        for (int i = 0; i < NISS; ++i) dst[i * 64 + lane] = src[i * 64 + lane];
    }
    if constexpr (H > 0) {
        float ps[H][4], pd[H][4];
        #pragma unroll
        for (int h = 0; h < H; ++h) {
            #pragma unroll
            for (int rr = 0; rr < 4; ++rr) { ps[h][rr] = 0.f; pd[h][rr] = 0.f; }
            #pragma unroll
            for (int tt = 0; tt < 4; ++tt) {
                int t = h * 4 + tt;
                float as = att_s[t * 16 + r];
                float ad = att_d[t * 16 + r];
                #pragma unroll
                for (int rr = 0; rr < 4; ++rr) {
                    ps[h][rr] += acc[t][rr] * as;
                    pd[h][rr] += acc[t][rr] * ad;
                }
            }
        }
        #pragma unroll
        for (int m = 1; m < 16; m <<= 1) {
            #pragma unroll
            for (int h = 0; h < H; ++h)
                #pragma unroll
                for (int rr = 0; rr < 4; ++rr) {
                    ps[h][rr] += __shfl_xor(ps[h][rr], m, 64);
                    pd[h][rr] += __shfl_xor(pd[h][rr], m, 64);
                }
        }
        if (r == 0) {
            #pragma unroll
            for (int rr = 0; rr < 4; ++rr) {
                int gm = m_base + q * 4 + rr;
                #pragma unroll
                for (int h = 0; h < H; ++h) {
                    a_srcO[gm * H + h] = ps[h][rr];
                    a_dstO[gm * H + h] = pd[h][rr];
                }
            }
        }
    }
}

// ---------------- GAT aggregation, H=4: ONE WAVE PER NODE, zero barriers ----------------
// 4 nodes/block. Lane j computes all 4 heads' premultiplied alphas for edge j into
// wave-private LDS; phase-3 gathers full 512B rows with scalar source bases.
__global__ void gat_agg4(const _Float16* __restrict__ h, const float* __restrict__ a_src,
                         const float* __restrict__ a_dst, const int* __restrict__ row_ptr,
                         const int* __restrict__ col, const float* __restrict__ bias,
                         _Float16* __restrict__ outp, int N) {
    int w = threadIdx.x >> 6, lane = threadIdx.x & 63;
    int i = blockIdx.x * 4 + w;
    if (i >= N) return;
    __shared__ float alphS[4][256];        // [wave][edge*4+head]
    __shared__ int   scolS[4][64];
    float* alph = alphS[w];
    int*   scol = scolS[w];
    int start = row_ptr[i], end = row_ptr[i + 1];
    int deg = end - start;
    float4 ad4 = *(const float4*)(a_dst + i * 4);
    int hh = lane >> 4;
    const _Float16* hb = h + lane * 4;     // per-lane column base (loop-invariant)
    float4 acc = make_float4(0.f, 0.f, 0.f, 0.f);

    if (deg <= 64) {
        float e0 = 0.f, e1 = 0.f, e2 = 0.f, e3 = 0.f; int s = 0;
        if (lane < deg) {
            s = col[start + lane];
            float4 as4 = *(const float4*)(a_src + (size_t)s * 4);
            e0 = __expf(leaky(as4.x + ad4.x));
            e1 = __expf(leaky(as4.y + ad4.y));
            e2 = __expf(leaky(as4.z + ad4.z));
            e3 = __expf(leaky(as4.w + ad4.w));
        }
        float s0 = wave_sum(e0), s1 = wave_sum(e1), s2 = wave_sum(e2), s3 = wave_sum(e3);
        if (lane < deg) {
            float4 al = make_float4(e0 / s0, e1 / s1, e2 / s2, e3 / s3);
            *(float4*)(alph + lane * 4) = al;
            scol[lane] = s;
        }
        // same-wave LDS RAW: hardware lgkmcnt ordering, no barrier needed
        int j = 0;
        for (; j + 3 < deg; j += 4) {
            int sA = __builtin_amdgcn_readfirstlane(scol[j]);
            int sB = __builtin_amdgcn_readfirstlane(scol[j + 1]);
            int sC = __builtin_amdgcn_readfirstlane(scol[j + 2]);
            int sD = __builtin_amdgcn_readfirstlane(scol[j + 3]);
            float aA = alph[j * 4 + hh],       aB = alph[(j + 1) * 4 + hh];
            float aC = alph[(j + 2) * 4 + hh], aD = alph[(j + 3) * 4 + hh];
            half4v vA = *(const half4v*)(hb + (size_t)sA * 256);
            half4v vB = *(const half4v*)(hb + (size_t)sB * 256);
            half4v vC = *(const half4v*)(hb + (size_t)sC * 256);
            half4v vD = *(const half4v*)(hb + (size_t)sD * 256);
            acc.x += aA * (float)vA[0] + aB * (float)vB[0] + aC * (float)vC[0] + aD * (float)vD[0];
            acc.y += aA * (float)vA[1] + aB * (float)vB[1] + aC * (float)vC[1] + aD * (float)vD[1];
            acc.z += aA * (float)vA[2] + aB * (float)vB[2] + aC * (float)vC[2] + aD * (float)vD[2];
            acc.w += aA * (float)vA[3] + aB * (float)vB[3] + aC * (float)vC[3] + aD * (float)vD[3];
        }
        for (; j < deg; ++j) {
            int sA = __builtin_amdgcn_readfirstlane(scol[j]);
            float aA = alph[j * 4 + hh];
            half4v vA = *(const half4v*)(hb + (size_t)sA * 256);
            acc.x += aA * (float)vA[0]; acc.y += aA * (float)vA[1];
            acc.z += aA * (float)vA[2]; acc.w += aA * (float)vA[3];
        }
    } else {
        float t0 = 0.f, t1 = 0.f, t2 = 0.f, t3 = 0.f;
        for (int j = start + lane; j < end; j += 64) {
            int s = col[j];
            float4 as4 = *(const float4*)(a_src + (size_t)s * 4);
            t0 += __expf(leaky(as4.x + ad4.x));
            t1 += __expf(leaky(as4.y + ad4.y));
            t2 += __expf(leaky(as4.z + ad4.z));
            t3 += __expf(leaky(as4.w + ad4.w));
        }
        t0 = wave_sum(t0); t1 = wave_sum(t1); t2 = wave_sum(t2); t3 = wave_sum(t3);
        float adh = (hh == 0) ? ad4.x : (hh == 1) ? ad4.y : (hh == 2) ? ad4.z : ad4.w;
        float ih  = 1.0f / ((hh == 0) ? t0 : (hh == 1) ? t1 : (hh == 2) ? t2 : t3);
        for (int j = start; j < end; ++j) {
            int s = col[j];                 // wave-uniform -> scalar load
            float asv = a_src[(size_t)s * 4 + hh];
            float alpha = __expf(leaky(asv + adh)) * ih;
            half4v v = *(const half4v*)(hb + (size_t)s * 256);
            acc.x += alpha * (float)v[0]; acc.y += alpha * (float)v[1];
            acc.z += alpha * (float)v[2]; acc.w += alpha * (float)v[3];
        }
    }
    float4 bv = *(const float4*)(bias + lane * 4);
    half4v o;
    o[0] = (_Float16)leaky(acc.x + bv.x);
    o[1] = (_Float16)leaky(acc.y + bv.y);
    o[2] = (_Float16)leaky(acc.z + bv.z);
    o[3] = (_Float16)leaky(acc.w + bv.w);
    *(half4v*)(outp + (size_t)i * 256 + lane * 4) = o;
}

// ---------------- GAT layer-2 aggregation + leaky + LayerNorm + residual, fused ----------
// ONE WAVE PER NODE (4/block). Subgroup (16 lanes) = one edge; after xor-reduce every
// lane holds the full row -> LN stats via 8 shfl; writes hresh fp16 directly.
__global__ void gat_agg1_ln(const _Float16* __restrict__ h, const float* __restrict__ a_src,
                            const float* __restrict__ a_dst, const int* __restrict__ row_ptr,
                            const int* __restrict__ col, const float* __restrict__ bias,
                            const float* __restrict__ lin, const float* __restrict__ gamma,
                            const float* __restrict__ beta, _Float16* __restrict__ hresh,
                            int N) {
    int w = threadIdx.x >> 6, lane = threadIdx.x & 63;
    int i = blockIdx.x * 4 + w;
    if (i >= N) return;
    __shared__ float alphS[4][64];
    __shared__ int   scolS[4][64];
    float* alph = alphS[w];
    int*   scol = scolS[w];
    int start = row_ptr[i], end = row_ptr[i + 1];
    int deg = end - start;
    float ad = a_dst[i];
    int sub = lane >> 4;
    int c4 = (lane & 15) * 4;
    float4 acc = make_float4(0.f, 0.f, 0.f, 0.f);

    if (deg <= 64) {
        float e = 0.f; int s = 0;
        if (lane < deg) {
            s = col[start + lane];
            e = __expf(leaky(a_src[s] + ad));
        }
        float ss = wave_sum(e);
        if (lane < deg) { alph[lane] = e / ss; scol[lane] = s; }
        int j = sub;
        for (; j + 4 < deg; j += 8) {
            int s0 = scol[j], s1 = scol[j + 4];
            float a0 = alph[j], a1 = alph[j + 4];
            half4v v0 = *(const half4v*)(h + (size_t)s0 * 64 + c4);
            half4v v1 = *(const half4v*)(h + (size_t)s1 * 64 + c4);
            acc.x += a0 * (float)v0[0] + a1 * (float)v1[0];
            acc.y += a0 * (float)v0[1] + a1 * (float)v1[1];
            acc.z += a0 * (float)v0[2] + a1 * (float)v1[2];
            acc.w += a0 * (float)v0[3] + a1 * (float)v1[3];
        }
        for (; j < deg; j += 4) {
            int s = scol[j];
            float a0 = alph[j];
            half4v v = *(const half4v*)(h + (size_t)s * 64 + c4);
            acc.x += a0 * (float)v[0]; acc.y += a0 * (float)v[1];
            acc.z += a0 * (float)v[2]; acc.w += a0 * (float)v[3];
        }
    } else {
        float ssum = 0.f;
        for (int j = start + lane; j < end; j += 64)
            ssum += __expf(leaky(a_src[col[j]] + ad));
        ssum = wave_sum(ssum);
        float inv = 1.0f / ssum;
        for (int j = start + sub; j < end; j += 4) {
            int s = col[j];
            float alpha = __expf(leaky(a_src[s] + ad)) * inv;
            half4v v = *(const half4v*)(h + (size_t)s * 64 + c4);
            acc.x += alpha * (float)v[0]; acc.y += alpha * (float)v[1];
            acc.z += alpha * (float)v[2]; acc.w += alpha * (float)v[3];
        }
    }
    #pragma unroll
    for (int o = 16; o <= 32; o <<= 1) {
        acc.x += __shfl_xor(acc.x, o, 64);
        acc.y += __shfl_xor(acc.y, o, 64);
        acc.z += __shfl_xor(acc.z, o, 64);
        acc.w += __shfl_xor(acc.w, o, 64);
    }
    // every lane now holds the full sums for its 4 channels (4 identical copies)
    float4 bv = *(const float4*)(bias + c4);
    float o0 = leaky(acc.x + bv.x), o1 = leaky(acc.y + bv.y);
    float o2 = leaky(acc.z + bv.z), o3 = leaky(acc.w + bv.w);
    // LayerNorm over 64 channels (channels live on lane&15 groups; xor 1,2,4,8)
    float ls = o0 + o1 + o2 + o3;
    #pragma unroll
    for (int o = 1; o <= 8; o <<= 1) ls += __shfl_xor(ls, o, 64);
    float mu = ls * (1.0f / 64.0f);
    float d0 = o0 - mu, d1 = o1 - mu, d2 = o2 - mu, d3 = o3 - mu;
    float lq = d0 * d0 + d1 * d1 + d2 * d2 + d3 * d3;
    #pragma unroll
    for (int o = 1; o <= 8; o <<= 1) lq += __shfl_xor(lq, o, 64);
    float rstd = rsqrtf(lq * (1.0f / 64.0f) + LN_EPS);
    float4 g4 = *(const float4*)(gamma + c4);
    float4 b4 = *(const float4*)(beta + c4);
    float4 l4 = *(const float4*)(lin + (size_t)i * 64 + c4);
    if (sub == 0) {
        half4v hv;
        hv[0] = (_Float16)(d0 * rstd * g4.x + b4.x + l4.x);
        hv[1] = (_Float16)(d1 * rstd * g4.y + b4.y + l4.y);
        hv[2] = (_Float16)(d2 * rstd * g4.z + b4.z + l4.z);
        hv[3] = (_Float16)(d3 * rstd * g4.w + b4.w + l4.w);
        *(half4v*)(hresh + (size_t)i * 64 + c4) = hv;
    }
}

// ---------------- gemm3 + GRU gates + FC head, fused ----------------
// gi = A@B^T + b_ih staged to wave-private LDS (fp16), then GRU+FC epilogue:
// quad q owns rows q*4..q*4+3; lane r owns channels r*4..r*4+3.
__global__ void gemm_gru(const _Float16* __restrict__ A, const _Float16* __restrict__ B,
                         const float* __restrict__ b_ih, const float* __restrict__ b_hh,
                         const float* __restrict__ fc_w, const float* __restrict__ fc_b,
                         float* __restrict__ outp, int M) {
    const int K = 64, NT = 12, Nc = 192;
    __shared__ __align__(16) _Float16 st[4][16 * 192];
    int w = threadIdx.x >> 6, lane = threadIdx.x & 63;
    int m_base = blockIdx.x * 64 + w * 16;
    if (m_base >= M) return;
    int r = lane & 15, q = lane >> 4;
    const _Float16* ap = A + (size_t)(m_base + r) * K + q * 8;
    const _Float16* bp = B + (size_t)r * K + q * 8;
    floatx4 acc[NT];
    #pragma unroll
    for (int t = 0; t < NT; ++t) acc[t] = (floatx4){0.f, 0.f, 0.f, 0.f};
    #pragma unroll
    for (int k0 = 0; k0 < K; k0 += 32) {
        half8 a = *(const half8*)(ap + k0);
        #pragma unroll
        for (int t = 0; t < NT; ++t) {
            half8 b = *(const half8*)(bp + (size_t)t * 16 * K + k0);
            acc[t] = __builtin_amdgcn_mfma_f32_16x16x32_f16(a, b, acc[t], 0, 0, 0);
        }
    }
    _Float16* sw = st[w];
    #pragma unroll
    for (int t = 0; t < NT; ++t) {
        int cc = t * 16 + r;
        float bv = b_ih[cc];
        #pragma unroll
        for (int rr = 0; rr < 4; ++rr)
            sw[(q * 4 + rr) * Nc + cc] = (_Float16)(acc[t][rr] + bv);
    }
    // GRU + FC (same-wave LDS RAW — lgkmcnt ordering, no barrier)
    float br_[4], bz_[4], bn_[4], f0_[4], f1_[4], f2_[4];
    *(float4*)br_ = *(const float4*)(b_hh + r * 4);
    *(float4*)bz_ = *(const float4*)(b_hh + 64 + r * 4);
    *(float4*)bn_ = *(const float4*)(b_hh + 128 + r * 4);
    *(float4*)f0_ = *(const float4*)(fc_w + r * 4);
    *(float4*)f1_ = *(const float4*)(fc_w + 64 + r * 4);
    *(float4*)f2_ = *(const float4*)(fc_w + 128 + r * 4);
    #pragma unroll
    for (int rr = 0; rr < 4; ++rr) {
        int row = q * 4 + rr;
        const _Float16* g = sw + row * Nc;
        half4v ir4 = *(const half4v*)(g + r * 4);
        half4v iz4 = *(const half4v*)(g + 64 + r * 4);
        half4v in4 = *(const half4v*)(g + 128 + r * 4);
        float p0 = 0.f, p1 = 0.f, p2 = 0.f;
        #pragma unroll
        for (int k = 0; k < 4; ++k) {
            float rg = 1.0f / (1.0f + __expf(-((float)ir4[k] + br_[k])));
            float zg = 1.0f / (1.0f + __expf(-((float)iz4[k] + bz_[k])));
            float ng = tanhf((float)in4[k] + rg * bn_[k]);
            float hy = (1.0f - zg) * ng;
            p0 += hy * f0_[k]; p1 += hy * f1_[k]; p2 += hy * f2_[k];
        }
        #pragma unroll
        for (int o = 1; o <= 8; o <<= 1) {
            p0 += __shfl_xor(p0, o, 64);
            p1 += __shfl_xor(p1, o, 64);
            p2 += __shfl_xor(p2, o, 64);
        }
        if (r == 0) {
            int gm = m_base + row;
            outp[(size_t)gm * 3 + 0] = p0 + fc_b[0];
            outp[(size_t)gm * 3 + 1] = p1 + fc_b[1];
            outp[(size_t)gm * 3 + 2] = p2 + fc_b[2];
        }
    }
}

extern "C" void kernel_launch(void* const* d_in, const int* in_sizes, int n_in,
                              void* d_out, int out_size, void* d_ws, size_t ws_size,
                              hipStream_t stream) {
    const float* x        = (const float*)d_in[0];
    const int*   ei       = (const int*)d_in[1];
    const float* W1       = (const float*)d_in[2];
    const float* att_src1 = (const float*)d_in[3];
    const float* att_dst1 = (const float*)d_in[4];
    const float* b1       = (const float*)d_in[5];
    const float* W2       = (const float*)d_in[6];
    const float* att_src2 = (const float*)d_in[7];
    const float* att_dst2 = (const float*)d_in[8];
    const float* b2       = (const float*)d_in[9];
    const float* lin_w    = (const float*)d_in[10];
    const float* lin_b    = (const float*)d_in[11];
    const float* gamma    = (const float*)d_in[12];
    const float* beta     = (const float*)d_in[13];
    const float* w_ih     = (const float*)d_in[14];
    // d_in[15] = w_hh (unused: h0 == 0)
    const float* b_ih     = (const float*)d_in[16];
    const float* b_hh     = (const float*)d_in[17];
    const float* fc_w     = (const float*)d_in[18];
    const float* fc_b     = (const float*)d_in[19];
    float* out = (float*)d_out;

    const int N = N_NODES, E = N_EDGES;
    const int Etot = E + N;
    const int nb = (N + 255) / 256;       // 196 scan blocks
    char* ws = (char*)d_ws;

    size_t off = 0;
    auto alloc = [&](size_t bytes) {
        size_t o = off;
        off = (off + bytes + 255) & ~(size_t)255;
        return o;
    };
    int*      row_ptr = (int*)(ws + alloc((size_t)(N + 1) * 4));
    int*      col     = (int*)(ws + alloc((size_t)Etot * 4));
    int*      deg     = (int*)(ws + alloc((size_t)N * 4));
    int*      fill    = (int*)(ws + alloc((size_t)N * 4));
    int*      bsum    = (int*)(ws + alloc((size_t)nb * 4));
    float*    a_src1b = (float*)(ws + alloc((size_t)N * HEADS * 4));
    float*    a_dst1b = (float*)(ws + alloc((size_t)N * HEADS * 4));
    float*    a_src2b = (float*)(ws + alloc((size_t)N * 4));
    float*    a_dst2b = (float*)(ws + alloc((size_t)N * 4));
    _Float16* W1h     = (_Float16*)(ws + alloc((size_t)256 * 256 * 2));
    _Float16* W2h     = (_Float16*)(ws + alloc((size_t)64 * 256 * 2));
    _Float16* lin_wh  = (_Float16*)(ws + alloc((size_t)64 * 256 * 2));
    _Float16* w_ihh   = (_Float16*)(ws + alloc((size_t)192 * 64 * 2));
    // big region (64MB): xh@0 (25.6M), h1h@25.6M (25.6M), lin@51.2M (12.8M fp32).
    char* big = ws + alloc((size_t)64000000);
    _Float16* xh   = (_Float16*)big;
    _Float16* h1h  = (_Float16*)(big + 25600000);
    float*    lin  = (float*)(big + 51200000);
    // region r3 (25.6M): o1h (fp16 [N,256]); after gemm2 consumes it -> hresh (fp16 [N,64])
    char* r3 = ws + alloc((size_t)25600000);
    _Float16* o1h   = (_Float16*)r3;
    _Float16* hresh = (_Float16*)r3;
    // region r4 (6.4M): h2h (fp16 [N,64])
    char* r4 = ws + alloc((size_t)6400000);
    _Float16* h2h = (_Float16*)r4;

    hipMemsetAsync(deg, 0, (size_t)N * 4, stream);
    hipMemsetAsync(fill, 0, (size_t)N * 4, stream);

    // ---- CSR build ----
    count_kernel<<<(Etot + 255) / 256, 256, 0, stream>>>(ei + E, deg, E, Etot);
    scan_part<<<nb, 256, 0, stream>>>(deg, bsum, N);
    scan_top<<<1, 256, 0, stream>>>(bsum, nb);
    scan_final<<<nb, 256, 0, stream>>>(deg, bsum, row_ptr, N);
    scatter_kernel<<<(Etot + 255) / 256, 256, 0, stream>>>(ei, ei + E, row_ptr, fill, col, E, Etot);

    // ---- fp16 conversions (one kernel, 5 ranges) ----
    {
        CvtJob j0{x, xh, N * F_IN};
        CvtJob j1{W1, W1h, 256 * 256};
        CvtJob j2{W2, W2h, 64 * 256};
        CvtJob j3{lin_w, lin_wh, 64 * 256};
        CvtJob j4{w_ih, w_ihh, 192 * 64};
        int total4 = (j0.len + j1.len + j2.len + j3.len + j4.len) / 4;
        cvt_f16_multi<<<(total4 + 255) / 256, 256, 0, stream>>>(j0, j1, j2, j3, j4);
    }

    const int gmBlocks = (N + 63) / 64;   // 782
    const int aggBlocks = (N + 3) / 4;    // 12500 (one wave per node)

    // ---- GAT layer 1 GEMM (+att coefs) ----
    gemm_mfma<16, 4, _Float16><<<gmBlocks, 256, 0, stream>>>(xh, W1h, nullptr, h1h,
        att_src1, att_dst1, a_src1b, a_dst1b, N, 256, 0);
    gat_agg4<<<aggBlocks, 256, 0, stream>>>(h1h, a_src1b, a_dst1b, row_ptr, col, b1, o1h, N);

    // ---- residual projection: lin = x @ lin_w^T + lin_b (fp32 out) ----
    gemm_mfma<4, 0, float><<<gmBlocks, 256, 0, stream>>>(xh, lin_wh, lin_b, lin,
        nullptr, nullptr, nullptr, nullptr, N, 256, 1);

    // ---- GAT layer 2 GEMM (+att coefs) ----
    gemm_mfma<4, 1, _Float16><<<gmBlocks, 256, 0, stream>>>(o1h, W2h, nullptr, h2h,
        att_src2, att_dst2, a_src2b, a_dst2b, N, 256, 0);

    // ---- layer-2 aggregation + leaky + LN + residual -> hresh fp16 (fused) ----
    gat_agg1_ln<<<aggBlocks, 256, 0, stream>>>(h2h, a_src2b, a_dst2b, row_ptr, col, b2,
        lin, gamma, beta, hresh, N);

    // ---- GRU input GEMM + gates + FC head (fused) ----
    gemm_gru<<<gmBlocks, 256, 0, stream>>>(hresh, w_ihh, b_ih, b_hh, fc_w, fc_b, out, N);
}

// Round 11
// 443.235 us; speedup vs baseline: 1.2466x; 1.0019x over previous
//
#include <hip/hip_runtime.h>
#include <hip/hip_bf16.h>

#define N_NODES 50000
#define N_EDGES 800000
#define F_IN 256
#define HID 64
#define HEADS 4
#define NEG 0.2f
#define LN_EPS 1e-5f

typedef _Float16 half8 __attribute__((ext_vector_type(8)));
typedef _Float16 half4v __attribute__((ext_vector_type(4)));
typedef float floatx4 __attribute__((ext_vector_type(4)));

__device__ __forceinline__ float wave_sum(float v) {
    #pragma unroll
    for (int o = 32; o > 0; o >>= 1) v += __shfl_xor(v, o, 64);
    return v;
}
__device__ __forceinline__ int wave_sum_i(int v) {
    #pragma unroll
    for (int o = 32; o > 0; o >>= 1) v += __shfl_xor(v, o, 64);
    return v;
}
__device__ __forceinline__ float leaky(float x) { return x > 0.0f ? x : NEG * x; }

// ---------------- CSR build ----------------
__global__ void count_kernel(const int* __restrict__ dst, int* __restrict__ deg,
                             int E, int Etot) {
    int e = blockIdx.x * blockDim.x + threadIdx.x;
    if (e >= Etot) return;
    int d = (e < E) ? dst[e] : (e - E);   // tail = self loops
    atomicAdd(&deg[d], 1);
}

__global__ void scan_part(const int* __restrict__ deg, int* __restrict__ bsum, int N) {
    int tid = threadIdx.x;
    int i = blockIdx.x * 256 + tid;
    int v = (i < N) ? deg[i] : 0;
    int s = wave_sum_i(v);
    __shared__ int ws4[4];
    if ((tid & 63) == 0) ws4[tid >> 6] = s;
    __syncthreads();
    if (tid == 0) bsum[blockIdx.x] = ws4[0] + ws4[1] + ws4[2] + ws4[3];
}

__global__ void scan_top(int* __restrict__ bsum, int nb) {   // in-place exclusive
    __shared__ int sh[256];
    int t = threadIdx.x;
    int v = (t < nb) ? bsum[t] : 0;
    sh[t] = v;
    __syncthreads();
    for (int o = 1; o < 256; o <<= 1) {
        int u = (t >= o) ? sh[t - o] : 0;
        __syncthreads();
        sh[t] += u;
        __syncthreads();
    }
    if (t < nb) bsum[t] = sh[t] - v;    // exclusive
}

__global__ void scan_final(const int* __restrict__ deg, const int* __restrict__ bsum,
                           int* __restrict__ row_ptr, int N) {
    __shared__ int sh[256];
    int t = threadIdx.x;
    int i = blockIdx.x * 256 + t;
    int v = (i < N) ? deg[i] : 0;
    sh[t] = v;
    __syncthreads();
    for (int o = 1; o < 256; o <<= 1) {
        int u = (t >= o) ? sh[t - o] : 0;
        __syncthreads();
        sh[t] += u;
        __syncthreads();
    }
    if (i < N) row_ptr[i + 1] = bsum[blockIdx.x] + sh[t];   // inclusive prefix
    if (i == 0) row_ptr[0] = 0;
}

__global__ void scatter_kernel(const int* __restrict__ src, const int* __restrict__ dst,
                               const int* __restrict__ row_ptr, int* __restrict__ fill,
                               int* __restrict__ col, int E, int Etot) {
    int e = blockIdx.x * blockDim.x + threadIdx.x;
    if (e >= Etot) return;
    int s, d;
    if (e < E) { s = src[e]; d = dst[e]; }
    else       { s = d = e - E; }
    int pos = atomicAdd(&fill[d], 1);
    col[row_ptr[d] + pos] = s;
}

// ---------------- merged fp32 -> fp16 conversion over 5 ranges ----------------
struct CvtJob { const float* src; _Float16* dst; int len; };
__global__ void cvt_f16_multi(CvtJob j0, CvtJob j1, CvtJob j2, CvtJob j3, CvtJob j4) {
    int idx = (blockIdx.x * blockDim.x + threadIdx.x) * 4;
    const float* s; _Float16* d; int rel = idx;
    if      (rel < j0.len) { s = j0.src; d = j0.dst; }
    else if ((rel -= j0.len) < j1.len) { s = j1.src; d = j1.dst; }
    else if ((rel -= j1.len) < j2.len) { s = j2.src; d = j2.dst; }
    else if ((rel -= j2.len) < j3.len) { s = j3.src; d = j3.dst; }
    else if ((rel -= j3.len) < j4.len) { s = j4.src; d = j4.dst; }
    else return;
    float4 v = *(const float4*)(s + rel);
    half4v h;
    h[0] = (_Float16)v.x; h[1] = (_Float16)v.y;
    h[2] = (_Float16)v.z; h[3] = (_Float16)v.w;
    *(half4v*)(d + rel) = h;
}

// ---------------- generic fp16 MFMA GEMM + optional att epilogue (LDS-staged stores) -----
// __launch_bounds__(256,2): 256-VGPR budget so all NT B-fragments stay in registers.
// (Default heuristic capped arch-VGPRs at ~52 -> B-loads serialized in batches with an
// L2 round-trip between each: 75us at 3% MfmaUtil for gemm1 in R10.)
template<int NT, int H, typename OutT>
__global__ __launch_bounds__(256, 2)
void gemm_mfma(const _Float16* __restrict__ A, const _Float16* __restrict__ B,
               const float* __restrict__ bias, OutT* __restrict__ Cout,
               const float* __restrict__ att_s, const float* __restrict__ att_d,
               float* __restrict__ a_srcO, float* __restrict__ a_dstO,
               int M, int K, int add_bias) {
    constexpr int TILEB = 16 * NT * 16 * sizeof(OutT);   // per-wave staged bytes
    __shared__ __align__(16) char smem[4 * TILEB];
    int w = threadIdx.x >> 6, lane = threadIdx.x & 63;
    int m_base = blockIdx.x * 64 + w * 16;
    if (m_base >= M) return;
    int r = lane & 15, q = lane >> 4;
    const _Float16* ap = A + (size_t)(m_base + r) * K + q * 8;
    const _Float16* bp = B + (size_t)r * K + q * 8;
    floatx4 acc[NT];
    #pragma unroll
    for (int t = 0; t < NT; ++t) acc[t] = (floatx4){0.f, 0.f, 0.f, 0.f};
    for (int k0 = 0; k0 < K; k0 += 32) {
        half8 a = *(const half8*)(ap + k0);
        half8 b[NT];
        #pragma unroll
        for (int t = 0; t < NT; ++t)
            b[t] = *(const half8*)(bp + (size_t)t * 16 * K + k0);
        #pragma unroll
        for (int t = 0; t < NT; ++t)
            acc[t] = __builtin_amdgcn_mfma_f32_16x16x32_f16(a, b[t], acc[t], 0, 0, 0);
    }
    const int Nc = NT * 16;
    OutT* st = (OutT*)(smem + w * TILEB);
    #pragma unroll
    for (int t = 0; t < NT; ++t) {
        int cc = t * 16 + r;
        float bv = add_bias ? bias[cc] : 0.0f;
        #pragma unroll
        for (int rr = 0; rr < 4; ++rr)
            st[(q * 4 + rr) * Nc + cc] = (OutT)(acc[t][rr] + bv);
    }
    {
        constexpr int NISS = TILEB / 1024;               // 1KB coalesced issues
        const int4* src = (const int4*)st;
        int4* dst = (int4*)((char*)Cout + (size_t)m_base * (Nc * sizeof(OutT)));
        #pragma unroll
        for (int i = 0; i < NISS; ++i) dst[i * 64 + lane] = src[i * 64 + lane];
    }
    if constexpr (H > 0) {
        float ps[H][4], pd[H][4];
        #pragma unroll
        for (int h = 0; h < H; ++h) {
            #pragma unroll
            for (int rr = 0; rr < 4; ++rr) { ps[h][rr] = 0.f; pd[h][rr] = 0.f; }
            #pragma unroll
            for (int tt = 0; tt < 4; ++tt) {
                int t = h * 4 + tt;
                float as = att_s[t * 16 + r];
                float ad = att_d[t * 16 + r];
                #pragma unroll
                for (int rr = 0; rr < 4; ++rr) {
                    ps[h][rr] += acc[t][rr] * as;
                    pd[h][rr] += acc[t][rr] * ad;
                }
            }
        }
        #pragma unroll
        for (int m = 1; m < 16; m <<= 1) {
            #pragma unroll
            for (int h = 0; h < H; ++h)
                #pragma unroll
                for (int rr = 0; rr < 4; ++rr) {
                    ps[h][rr] += __shfl_xor(ps[h][rr], m, 64);
                    pd[h][rr] += __shfl_xor(pd[h][rr], m, 64);
                }
        }
        if (r == 0) {
            #pragma unroll
            for (int rr = 0; rr < 4; ++rr) {
                int gm = m_base + q * 4 + rr;
                #pragma unroll
                for (int h = 0; h < H; ++h) {
                    a_srcO[gm * H + h] = ps[h][rr];
                    a_dstO[gm * H + h] = pd[h][rr];
                }
            }
        }
    }
}

// ---------------- GAT aggregation, H=4: ONE WAVE PER NODE, zero barriers ----------------
__global__ void gat_agg4(const _Float16* __restrict__ h, const float* __restrict__ a_src,
                         const float* __restrict__ a_dst, const int* __restrict__ row_ptr,
                         const int* __restrict__ col, const float* __restrict__ bias,
                         _Float16* __restrict__ outp, int N) {
    int w = threadIdx.x >> 6, lane = threadIdx.x & 63;
    int i = blockIdx.x * 4 + w;
    if (i >= N) return;
    __shared__ float alphS[4][256];        // [wave][edge*4+head]
    __shared__ int   scolS[4][64];
    float* alph = alphS[w];
    int*   scol = scolS[w];
    int start = row_ptr[i], end = row_ptr[i + 1];
    int deg = end - start;
    float4 ad4 = *(const float4*)(a_dst + i * 4);
    int hh = lane >> 4;
    const _Float16* hb = h + lane * 4;     // per-lane column base (loop-invariant)
    float4 acc = make_float4(0.f, 0.f, 0.f, 0.f);

    if (deg <= 64) {
        float e0 = 0.f, e1 = 0.f, e2 = 0.f, e3 = 0.f; int s = 0;
        if (lane < deg) {
            s = col[start + lane];
            float4 as4 = *(const float4*)(a_src + (size_t)s * 4);
            e0 = __expf(leaky(as4.x + ad4.x));
            e1 = __expf(leaky(as4.y + ad4.y));
            e2 = __expf(leaky(as4.z + ad4.z));
            e3 = __expf(leaky(as4.w + ad4.w));
        }
        float s0 = wave_sum(e0), s1 = wave_sum(e1), s2 = wave_sum(e2), s3 = wave_sum(e3);
        if (lane < deg) {
            float4 al = make_float4(e0 / s0, e1 / s1, e2 / s2, e3 / s3);
            *(float4*)(alph + lane * 4) = al;
            scol[lane] = s;
        }
        // same-wave LDS RAW: hardware lgkmcnt ordering, no barrier needed
        int j = 0;
        for (; j + 3 < deg; j += 4) {
            int sA = __builtin_amdgcn_readfirstlane(scol[j]);
            int sB = __builtin_amdgcn_readfirstlane(scol[j + 1]);
            int sC = __builtin_amdgcn_readfirstlane(scol[j + 2]);
            int sD = __builtin_amdgcn_readfirstlane(scol[j + 3]);
            float aA = alph[j * 4 + hh],       aB = alph[(j + 1) * 4 + hh];
            float aC = alph[(j + 2) * 4 + hh], aD = alph[(j + 3) * 4 + hh];
            half4v vA = *(const half4v*)(hb + (size_t)sA * 256);
            half4v vB = *(const half4v*)(hb + (size_t)sB * 256);
            half4v vC = *(const half4v*)(hb + (size_t)sC * 256);
            half4v vD = *(const half4v*)(hb + (size_t)sD * 256);
            acc.x += aA * (float)vA[0] + aB * (float)vB[0] + aC * (float)vC[0] + aD * (float)vD[0];
            acc.y += aA * (float)vA[1] + aB * (float)vB[1] + aC * (float)vC[1] + aD * (float)vD[1];
            acc.z += aA * (float)vA[2] + aB * (float)vB[2] + aC * (float)vC[2] + aD * (float)vD[2];
            acc.w += aA * (float)vA[3] + aB * (float)vB[3] + aC * (float)vC[3] + aD * (float)vD[3];
        }
        for (; j < deg; ++j) {
            int sA = __builtin_amdgcn_readfirstlane(scol[j]);
            float aA = alph[j * 4 + hh];
            half4v vA = *(const half4v*)(hb + (size_t)sA * 256);
            acc.x += aA * (float)vA[0]; acc.y += aA * (float)vA[1];
            acc.z += aA * (float)vA[2]; acc.w += aA * (float)vA[3];
        }
    } else {
        float t0 = 0.f, t1 = 0.f, t2 = 0.f, t3 = 0.f;
        for (int j = start + lane; j < end; j += 64) {
            int s = col[j];
            float4 as4 = *(const float4*)(a_src + (size_t)s * 4);
            t0 += __expf(leaky(as4.x + ad4.x));
            t1 += __expf(leaky(as4.y + ad4.y));
            t2 += __expf(leaky(as4.z + ad4.z));
            t3 += __expf(leaky(as4.w + ad4.w));
        }
        t0 = wave_sum(t0); t1 = wave_sum(t1); t2 = wave_sum(t2); t3 = wave_sum(t3);
        float adh = (hh == 0) ? ad4.x : (hh == 1) ? ad4.y : (hh == 2) ? ad4.z : ad4.w;
        float ih  = 1.0f / ((hh == 0) ? t0 : (hh == 1) ? t1 : (hh == 2) ? t2 : t3);
        for (int j = start; j < end; ++j) {
            int s = col[j];                 // wave-uniform -> scalar load
            float asv = a_src[(size_t)s * 4 + hh];
            float alpha = __expf(leaky(asv + adh)) * ih;
            half4v v = *(const half4v*)(hb + (size_t)s * 256);
            acc.x += alpha * (float)v[0]; acc.y += alpha * (float)v[1];
            acc.z += alpha * (float)v[2]; acc.w += alpha * (float)v[3];
        }
    }
    float4 bv = *(const float4*)(bias + lane * 4);
    half4v o;
    o[0] = (_Float16)leaky(acc.x + bv.x);
    o[1] = (_Float16)leaky(acc.y + bv.y);
    o[2] = (_Float16)leaky(acc.z + bv.z);
    o[3] = (_Float16)leaky(acc.w + bv.w);
    *(half4v*)(outp + (size_t)i * 256 + lane * 4) = o;
}

// ---------------- GAT layer-2 aggregation + leaky + LayerNorm + residual, fused ----------
__global__ void gat_agg1_ln(const _Float16* __restrict__ h, const float* __restrict__ a_src,
                            const float* __restrict__ a_dst, const int* __restrict__ row_ptr,
                            const int* __restrict__ col, const float* __restrict__ bias,
                            const float* __restrict__ lin, const float* __restrict__ gamma,
                            const float* __restrict__ beta, _Float16* __restrict__ hresh,
                            int N) {
    int w = threadIdx.x >> 6, lane = threadIdx.x & 63;
    int i = blockIdx.x * 4 + w;
    if (i >= N) return;
    __shared__ float alphS[4][64];
    __shared__ int   scolS[4][64];
    float* alph = alphS[w];
    int*   scol = scolS[w];
    int start = row_ptr[i], end = row_ptr[i + 1];
    int deg = end - start;
    float ad = a_dst[i];
    int sub = lane >> 4;
    int c4 = (lane & 15) * 4;
    float4 acc = make_float4(0.f, 0.f, 0.f, 0.f);

    if (deg <= 64) {
        float e = 0.f; int s = 0;
        if (lane < deg) {
            s = col[start + lane];
            e = __expf(leaky(a_src[s] + ad));
        }
        float ss = wave_sum(e);
        if (lane < deg) { alph[lane] = e / ss; scol[lane] = s; }
        int j = sub;
        for (; j + 4 < deg; j += 8) {
            int s0 = scol[j], s1 = scol[j + 4];
            float a0 = alph[j], a1 = alph[j + 4];
            half4v v0 = *(const half4v*)(h + (size_t)s0 * 64 + c4);
            half4v v1 = *(const half4v*)(h + (size_t)s1 * 64 + c4);
            acc.x += a0 * (float)v0[0] + a1 * (float)v1[0];
            acc.y += a0 * (float)v0[1] + a1 * (float)v1[1];
            acc.z += a0 * (float)v0[2] + a1 * (float)v1[2];
            acc.w += a0 * (float)v0[3] + a1 * (float)v1[3];
        }
        for (; j < deg; j += 4) {
            int s = scol[j];
            float a0 = alph[j];
            half4v v = *(const half4v*)(h + (size_t)s * 64 + c4);
            acc.x += a0 * (float)v[0]; acc.y += a0 * (float)v[1];
            acc.z += a0 * (float)v[2]; acc.w += a0 * (float)v[3];
        }
    } else {
        float ssum = 0.f;
        for (int j = start + lane; j < end; j += 64)
            ssum += __expf(leaky(a_src[col[j]] + ad));
        ssum = wave_sum(ssum);
        float inv = 1.0f / ssum;
        for (int j = start + sub; j < end; j += 4) {
            int s = col[j];
            float alpha = __expf(leaky(a_src[s] + ad)) * inv;
            half4v v = *(const half4v*)(h + (size_t)s * 64 + c4);
            acc.x += alpha * (float)v[0]; acc.y += alpha * (float)v[1];
            acc.z += alpha * (float)v[2]; acc.w += alpha * (float)v[3];
        }
    }
    #pragma unroll
    for (int o = 16; o <= 32; o <<= 1) {
        acc.x += __shfl_xor(acc.x, o, 64);
        acc.y += __shfl_xor(acc.y, o, 64);
        acc.z += __shfl_xor(acc.z, o, 64);
        acc.w += __shfl_xor(acc.w, o, 64);
    }
    float4 bv = *(const float4*)(bias + c4);
    float o0 = leaky(acc.x + bv.x), o1 = leaky(acc.y + bv.y);
    float o2 = leaky(acc.z + bv.z), o3 = leaky(acc.w + bv.w);
    float ls = o0 + o1 + o2 + o3;
    #pragma unroll
    for (int o = 1; o <= 8; o <<= 1) ls += __shfl_xor(ls, o, 64);
    float mu = ls * (1.0f / 64.0f);
    float d0 = o0 - mu, d1 = o1 - mu, d2 = o2 - mu, d3 = o3 - mu;
    float lq = d0 * d0 + d1 * d1 + d2 * d2 + d3 * d3;
    #pragma unroll
    for (int o = 1; o <= 8; o <<= 1) lq += __shfl_xor(lq, o, 64);
    float rstd = rsqrtf(lq * (1.0f / 64.0f) + LN_EPS);
    float4 g4 = *(const float4*)(gamma + c4);
    float4 b4 = *(const float4*)(beta + c4);
    float4 l4 = *(const float4*)(lin + (size_t)i * 64 + c4);
    if (sub == 0) {
        half4v hv;
        hv[0] = (_Float16)(d0 * rstd * g4.x + b4.x + l4.x);
        hv[1] = (_Float16)(d1 * rstd * g4.y + b4.y + l4.y);
        hv[2] = (_Float16)(d2 * rstd * g4.z + b4.z + l4.z);
        hv[3] = (_Float16)(d3 * rstd * g4.w + b4.w + l4.w);
        *(half4v*)(hresh + (size_t)i * 64 + c4) = hv;
    }
}

// ---------------- gemm3 + GRU gates + FC head, fused ----------------
__global__ __launch_bounds__(256, 2)
void gemm_gru(const _Float16* __restrict__ A, const _Float16* __restrict__ B,
              const float* __restrict__ b_ih, const float* __restrict__ b_hh,
              const float* __restrict__ fc_w, const float* __restrict__ fc_b,
              float* __restrict__ outp, int M) {
    const int K = 64, NT = 12, Nc = 192;
    __shared__ __align__(16) _Float16 st[4][16 * 192];
    int w = threadIdx.x >> 6, lane = threadIdx.x & 63;
    int m_base = blockIdx.x * 64 + w * 16;
    if (m_base >= M) return;
    int r = lane & 15, q = lane >> 4;
    const _Float16* ap = A + (size_t)(m_base + r) * K + q * 8;
    const _Float16* bp = B + (size_t)r * K + q * 8;
    floatx4 acc[NT];
    #pragma unroll
    for (int t = 0; t < NT; ++t) acc[t] = (floatx4){0.f, 0.f, 0.f, 0.f};
    #pragma unroll
    for (int k0 = 0; k0 < K; k0 += 32) {
        half8 a = *(const half8*)(ap + k0);
        half8 b[NT];
        #pragma unroll
        for (int t = 0; t < NT; ++t)
            b[t] = *(const half8*)(bp + (size_t)t * 16 * K + k0);
        #pragma unroll
        for (int t = 0; t < NT; ++t)
            acc[t] = __builtin_amdgcn_mfma_f32_16x16x32_f16(a, b[t], acc[t], 0, 0, 0);
    }
    _Float16* sw = st[w];
    #pragma unroll
    for (int t = 0; t < NT; ++t) {
        int cc = t * 16 + r;
        float bv = b_ih[cc];
        #pragma unroll
        for (int rr = 0; rr < 4; ++rr)
            sw[(q * 4 + rr) * Nc + cc] = (_Float16)(acc[t][rr] + bv);
    }
    // GRU + FC (same-wave LDS RAW — lgkmcnt ordering, no barrier)
    float br_[4], bz_[4], bn_[4], f0_[4], f1_[4], f2_[4];
    *(float4*)br_ = *(const float4*)(b_hh + r * 4);
    *(float4*)bz_ = *(const float4*)(b_hh + 64 + r * 4);
    *(float4*)bn_ = *(const float4*)(b_hh + 128 + r * 4);
    *(float4*)f0_ = *(const float4*)(fc_w + r * 4);
    *(float4*)f1_ = *(const float4*)(fc_w + 64 + r * 4);
    *(float4*)f2_ = *(const float4*)(fc_w + 128 + r * 4);
    #pragma unroll
    for (int rr = 0; rr < 4; ++rr) {
        int row = q * 4 + rr;
        const _Float16* g = sw + row * Nc;
        half4v ir4 = *(const half4v*)(g + r * 4);
        half4v iz4 = *(const half4v*)(g + 64 + r * 4);
        half4v in4 = *(const half4v*)(g + 128 + r * 4);
        float p0 = 0.f, p1 = 0.f, p2 = 0.f;
        #pragma unroll
        for (int k = 0; k < 4; ++k) {
            float rg = 1.0f / (1.0f + __expf(-((float)ir4[k] + br_[k])));
            float zg = 1.0f / (1.0f + __expf(-((float)iz4[k] + bz_[k])));
            float ng = tanhf((float)in4[k] + rg * bn_[k]);
            float hy = (1.0f - zg) * ng;
            p0 += hy * f0_[k]; p1 += hy * f1_[k]; p2 += hy * f2_[k];
        }
        #pragma unroll
        for (int o = 1; o <= 8; o <<= 1) {
            p0 += __shfl_xor(p0, o, 64);
            p1 += __shfl_xor(p1, o, 64);
            p2 += __shfl_xor(p2, o, 64);
        }
        if (r == 0) {
            int gm = m_base + row;
            outp[(size_t)gm * 3 + 0] = p0 + fc_b[0];
            outp[(size_t)gm * 3 + 1] = p1 + fc_b[1];
            outp[(size_t)gm * 3 + 2] = p2 + fc_b[2];
        }
    }
}

extern "C" void kernel_launch(void* const* d_in, const int* in_sizes, int n_in,
                              void* d_out, int out_size, void* d_ws, size_t ws_size,
                              hipStream_t stream) {
    const float* x        = (const float*)d_in[0];
    const int*   ei       = (const int*)d_in[1];
    const float* W1       = (const float*)d_in[2];
    const float* att_src1 = (const float*)d_in[3];
    const float* att_dst1 = (const float*)d_in[4];
    const float* b1       = (const float*)d_in[5];
    const float* W2       = (const float*)d_in[6];
    const float* att_src2 = (const float*)d_in[7];
    const float* att_dst2 = (const float*)d_in[8];
    const float* b2       = (const float*)d_in[9];
    const float* lin_w    = (const float*)d_in[10];
    const float* lin_b    = (const float*)d_in[11];
    const float* gamma    = (const float*)d_in[12];
    const float* beta     = (const float*)d_in[13];
    const float* w_ih     = (const float*)d_in[14];
    // d_in[15] = w_hh (unused: h0 == 0)
    const float* b_ih     = (const float*)d_in[16];
    const float* b_hh     = (const float*)d_in[17];
    const float* fc_w     = (const float*)d_in[18];
    const float* fc_b     = (const float*)d_in[19];
    float* out = (float*)d_out;

    const int N = N_NODES, E = N_EDGES;
    const int Etot = E + N;
    const int nb = (N + 255) / 256;       // 196 scan blocks
    char* ws = (char*)d_ws;

    size_t off = 0;
    auto alloc = [&](size_t bytes) {
        size_t o = off;
        off = (off + bytes + 255) & ~(size_t)255;
        return o;
    };
    int*      row_ptr = (int*)(ws + alloc((size_t)(N + 1) * 4));
    int*      col     = (int*)(ws + alloc((size_t)Etot * 4));
    int*      deg     = (int*)(ws + alloc((size_t)N * 4));
    int*      fill    = (int*)(ws + alloc((size_t)N * 4));
    int*      bsum    = (int*)(ws + alloc((size_t)nb * 4));
    float*    a_src1b = (float*)(ws + alloc((size_t)N * HEADS * 4));
    float*    a_dst1b = (float*)(ws + alloc((size_t)N * HEADS * 4));
    float*    a_src2b = (float*)(ws + alloc((size_t)N * 4));
    float*    a_dst2b = (float*)(ws + alloc((size_t)N * 4));
    _Float16* W1h     = (_Float16*)(ws + alloc((size_t)256 * 256 * 2));
    _Float16* W2h     = (_Float16*)(ws + alloc((size_t)64 * 256 * 2));
    _Float16* lin_wh  = (_Float16*)(ws + alloc((size_t)64 * 256 * 2));
    _Float16* w_ihh   = (_Float16*)(ws + alloc((size_t)192 * 64 * 2));
    // big region (64MB): xh@0 (25.6M), h1h@25.6M (25.6M), lin@51.2M (12.8M fp32).
    char* big = ws + alloc((size_t)64000000);
    _Float16* xh   = (_Float16*)big;
    _Float16* h1h  = (_Float16*)(big + 25600000);
    float*    lin  = (float*)(big + 51200000);
    // region r3 (25.6M): o1h (fp16 [N,256]); after gemm2 consumes it -> hresh (fp16 [N,64])
    char* r3 = ws + alloc((size_t)25600000);
    _Float16* o1h   = (_Float16*)r3;
    _Float16* hresh = (_Float16*)r3;
    // region r4 (6.4M): h2h (fp16 [N,64])
    char* r4 = ws + alloc((size_t)6400000);
    _Float16* h2h = (_Float16*)r4;

    hipMemsetAsync(deg, 0, (size_t)N * 4, stream);
    hipMemsetAsync(fill, 0, (size_t)N * 4, stream);

    // ---- CSR build ----
    count_kernel<<<(Etot + 255) / 256, 256, 0, stream>>>(ei + E, deg, E, Etot);
    scan_part<<<nb, 256, 0, stream>>>(deg, bsum, N);
    scan_top<<<1, 256, 0, stream>>>(bsum, nb);
    scan_final<<<nb, 256, 0, stream>>>(deg, bsum, row_ptr, N);
    scatter_kernel<<<(Etot + 255) / 256, 256, 0, stream>>>(ei, ei + E, row_ptr, fill, col, E, Etot);

    // ---- fp16 conversions (one kernel, 5 ranges) ----
    {
        CvtJob j0{x, xh, N * F_IN};
        CvtJob j1{W1, W1h, 256 * 256};
        CvtJob j2{W2, W2h, 64 * 256};
        CvtJob j3{lin_w, lin_wh, 64 * 256};
        CvtJob j4{w_ih, w_ihh, 192 * 64};
        int total4 = (j0.len + j1.len + j2.len + j3.len + j4.len) / 4;
        cvt_f16_multi<<<(total4 + 255) / 256, 256, 0, stream>>>(j0, j1, j2, j3, j4);
    }

    const int gmBlocks = (N + 63) / 64;   // 782
    const int aggBlocks = (N + 3) / 4;    // 12500 (one wave per node)

    // ---- GAT layer 1 GEMM (+att coefs) ----
    gemm_mfma<16, 4, _Float16><<<gmBlocks, 256, 0, stream>>>(xh, W1h, nullptr, h1h,
        att_src1, att_dst1, a_src1b, a_dst1b, N, 256, 0);
    gat_agg4<<<aggBlocks, 256, 0, stream>>>(h1h, a_src1b, a_dst1b, row_ptr, col, b1, o1h, N);

    // ---- residual projection: lin = x @ lin_w^T + lin_b (fp32 out) ----
    gemm_mfma<4, 0, float><<<gmBlocks, 256, 0, stream>>>(xh, lin_wh, lin_b, lin,
        nullptr, nullptr, nullptr, nullptr, N, 256, 1);

    // ---- GAT layer 2 GEMM (+att coefs) ----
    gemm_mfma<4, 1, _Float16><<<gmBlocks, 256, 0, stream>>>(o1h, W2h, nullptr, h2h,
        att_src2, att_dst2, a_src2b, a_dst2b, N, 256, 0);

    // ---- layer-2 aggregation + leaky + LN + residual -> hresh fp16 (fused) ----
    gat_agg1_ln<<<aggBlocks, 256, 0, stream>>>(h2h, a_src2b, a_dst2b, row_ptr, col, b2,
        lin, gamma, beta, hresh, N);

    // ---- GRU input GEMM + gates + FC head (fused) ----
    gemm_gru<<<gmBlocks, 256, 0, stream>>>(hresh, w_ihh, b_ih, b_hh, fc_w, fc_b, out, N);
}

// Round 12
// 370.268 us; speedup vs baseline: 1.4922x; 1.1971x over previous
//
#include <hip/hip_runtime.h>
#include <hip/hip_bf16.h>

#define N_NODES 50000
#define N_EDGES 800000
#define F_IN 256
#define HID 64
#define HEADS 4
#define NEG 0.2f
#define LN_EPS 1e-5f

typedef _Float16 half8 __attribute__((ext_vector_type(8)));
typedef _Float16 half4v __attribute__((ext_vector_type(4)));
typedef float floatx4 __attribute__((ext_vector_type(4)));

__device__ __forceinline__ float wave_sum(float v) {
    #pragma unroll
    for (int o = 32; o > 0; o >>= 1) v += __shfl_xor(v, o, 64);
    return v;
}
__device__ __forceinline__ int wave_sum_i(int v) {
    #pragma unroll
    for (int o = 32; o > 0; o >>= 1) v += __shfl_xor(v, o, 64);
    return v;
}
__device__ __forceinline__ float leaky(float x) { return x > 0.0f ? x : NEG * x; }

// ---------------- CSR build ----------------
__global__ void count_kernel(const int* __restrict__ dst, int* __restrict__ deg,
                             int E, int Etot) {
    int e = blockIdx.x * blockDim.x + threadIdx.x;
    if (e >= Etot) return;
    int d = (e < E) ? dst[e] : (e - E);   // tail = self loops
    atomicAdd(&deg[d], 1);
}

__global__ void scan_part(const int* __restrict__ deg, int* __restrict__ bsum, int N) {
    int tid = threadIdx.x;
    int i = blockIdx.x * 256 + tid;
    int v = (i < N) ? deg[i] : 0;
    int s = wave_sum_i(v);
    __shared__ int ws4[4];
    if ((tid & 63) == 0) ws4[tid >> 6] = s;
    __syncthreads();
    if (tid == 0) bsum[blockIdx.x] = ws4[0] + ws4[1] + ws4[2] + ws4[3];
}

__global__ void scan_top(int* __restrict__ bsum, int nb) {   // in-place exclusive
    __shared__ int sh[256];
    int t = threadIdx.x;
    int v = (t < nb) ? bsum[t] : 0;
    sh[t] = v;
    __syncthreads();
    for (int o = 1; o < 256; o <<= 1) {
        int u = (t >= o) ? sh[t - o] : 0;
        __syncthreads();
        sh[t] += u;
        __syncthreads();
    }
    if (t < nb) bsum[t] = sh[t] - v;    // exclusive
}

__global__ void scan_final(const int* __restrict__ deg, const int* __restrict__ bsum,
                           int* __restrict__ row_ptr, int N) {
    __shared__ int sh[256];
    int t = threadIdx.x;
    int i = blockIdx.x * 256 + t;
    int v = (i < N) ? deg[i] : 0;
    sh[t] = v;
    __syncthreads();
    for (int o = 1; o < 256; o <<= 1) {
        int u = (t >= o) ? sh[t - o] : 0;
        __syncthreads();
        sh[t] += u;
        __syncthreads();
    }
    if (i < N) row_ptr[i + 1] = bsum[blockIdx.x] + sh[t];   // inclusive prefix
    if (i == 0) row_ptr[0] = 0;
}

__global__ void scatter_kernel(const int* __restrict__ src, const int* __restrict__ dst,
                               const int* __restrict__ row_ptr, int* __restrict__ fill,
                               int* __restrict__ col, int E, int Etot) {
    int e = blockIdx.x * blockDim.x + threadIdx.x;
    if (e >= Etot) return;
    int s, d;
    if (e < E) { s = src[e]; d = dst[e]; }
    else       { s = d = e - E; }
    int pos = atomicAdd(&fill[d], 1);
    col[row_ptr[d] + pos] = s;
}

// ---------------- merged fp32 -> fp16 conversion over 5 ranges ----------------
struct CvtJob { const float* src; _Float16* dst; int len; };
__global__ void cvt_f16_multi(CvtJob j0, CvtJob j1, CvtJob j2, CvtJob j3, CvtJob j4) {
    int idx = (blockIdx.x * blockDim.x + threadIdx.x) * 4;
    const float* s; _Float16* d; int rel = idx;
    if      (rel < j0.len) { s = j0.src; d = j0.dst; }
    else if ((rel -= j0.len) < j1.len) { s = j1.src; d = j1.dst; }
    else if ((rel -= j1.len) < j2.len) { s = j2.src; d = j2.dst; }
    else if ((rel -= j2.len) < j3.len) { s = j3.src; d = j3.dst; }
    else if ((rel -= j3.len) < j4.len) { s = j4.src; d = j4.dst; }
    else return;
    float4 v = *(const float4*)(s + rel);
    half4v h;
    h[0] = (_Float16)v.x; h[1] = (_Float16)v.y;
    h[2] = (_Float16)v.z; h[3] = (_Float16)v.w;
    *(half4v*)(d + rel) = h;
}

// ---------------- fp16 MFMA GEMM, B staged through LDS + optional att epilogue -----------
// R10/R11 lesson: the compiler serializes per-wave global B-fragment loads (one vmcnt wait
// per fragment, ~300-700 cyc each -> 73us at 3% MfmaUtil). Fix: cooperative coalesced
// B-tile load into LDS (latency amortized across 256 threads), fragments via ds_read
// (~12 cyc each, serialization harmless). B rows padded to 40 halfs to spread banks.
// C-stage region aliases the B-tile (dead after the last K-loop barrier).
template<int NT, int H, typename OutT>
__global__ __launch_bounds__(256, 2)
void gemm_mfma(const _Float16* __restrict__ A, const _Float16* __restrict__ B,
               const float* __restrict__ bias, OutT* __restrict__ Cout,
               const float* __restrict__ att_s, const float* __restrict__ att_d,
               float* __restrict__ a_srcO, float* __restrict__ a_dstO,
               int M, int K, int add_bias) {
    constexpr int Nc = NT * 16;
    constexpr int BROW = 40;                               // 32 data + 8 pad halfs
    constexpr int BTILE = Nc * BROW * 2;                   // B-tile bytes
    constexpr int TILEB = 16 * Nc * sizeof(OutT);          // per-wave C-stage bytes
    constexpr int SM = (BTILE > 4 * TILEB) ? BTILE : 4 * TILEB;
    __shared__ __align__(16) char smem[SM];
    _Float16* sB = (_Float16*)smem;
    int tid = threadIdx.x;
    int w = tid >> 6, lane = tid & 63;
    int m_base = blockIdx.x * 64 + w * 16;
    bool active = (m_base < M);                            // wave-uniform; keep barriers!
    int r = lane & 15, q = lane >> 4;
    const _Float16* ap = A + (size_t)(m_base + r) * K + q * 8;
    floatx4 acc[NT];
    #pragma unroll
    for (int t = 0; t < NT; ++t) acc[t] = (floatx4){0.f, 0.f, 0.f, 0.f};
    half8 a_next = {};
    if (active) a_next = *(const half8*)ap;                // k0=0 prefetch
    for (int k0 = 0; k0 < K; k0 += 32) {
        // cooperative coalesced B-tile load: B[0:Nc, k0:k0+32]
        for (int i = tid; i < Nc * 4; i += 256) {
            int row = i >> 2, seg = i & 3;
            *(half8*)(sB + row * BROW + seg * 8) =
                *(const half8*)(B + (size_t)row * K + k0 + seg * 8);
        }
        __syncthreads();
        half8 a = a_next;
        if (active && k0 + 32 < K) a_next = *(const half8*)(ap + k0 + 32);
        if (active) {
            half8 b[NT];
            #pragma unroll
            for (int t = 0; t < NT; ++t)
                b[t] = *(const half8*)(sB + (t * 16 + r) * BROW + q * 8);
            #pragma unroll
            for (int t = 0; t < NT; ++t)
                acc[t] = __builtin_amdgcn_mfma_f32_16x16x32_f16(a, b[t], acc[t], 0, 0, 0);
        }
        __syncthreads();                                   // protect sB for next iter / C-stage
    }
    if (active) {
        OutT* st = (OutT*)(smem + w * TILEB);
        #pragma unroll
        for (int t = 0; t < NT; ++t) {
            int cc = t * 16 + r;
            float bv = add_bias ? bias[cc] : 0.0f;
            #pragma unroll
            for (int rr = 0; rr < 4; ++rr)
                st[(q * 4 + rr) * Nc + cc] = (OutT)(acc[t][rr] + bv);
        }
        constexpr int NISS = TILEB / 1024;                 // 1KB coalesced issues
        const int4* src = (const int4*)st;
        int4* dst = (int4*)((char*)Cout + (size_t)m_base * (Nc * sizeof(OutT)));
        #pragma unroll
        for (int i = 0; i < NISS; ++i) dst[i * 64 + lane] = src[i * 64 + lane];
        if constexpr (H > 0) {
            float ps[H][4], pd[H][4];
            #pragma unroll
            for (int h = 0; h < H; ++h) {
                #pragma unroll
                for (int rr = 0; rr < 4; ++rr) { ps[h][rr] = 0.f; pd[h][rr] = 0.f; }
                #pragma unroll
                for (int tt = 0; tt < 4; ++tt) {
                    int t = h * 4 + tt;
                    float as = att_s[t * 16 + r];
                    float ad = att_d[t * 16 + r];
                    #pragma unroll
                    for (int rr = 0; rr < 4; ++rr) {
                        ps[h][rr] += acc[t][rr] * as;
                        pd[h][rr] += acc[t][rr] * ad;
                    }
                }
            }
            #pragma unroll
            for (int m = 1; m < 16; m <<= 1) {
                #pragma unroll
                for (int h = 0; h < H; ++h)
                    #pragma unroll
                    for (int rr = 0; rr < 4; ++rr) {
                        ps[h][rr] += __shfl_xor(ps[h][rr], m, 64);
                        pd[h][rr] += __shfl_xor(pd[h][rr], m, 64);
                    }
            }
            if (r == 0) {
                #pragma unroll
                for (int rr = 0; rr < 4; ++rr) {
                    int gm = m_base + q * 4 + rr;
                    #pragma unroll
                    for (int h = 0; h < H; ++h) {
                        a_srcO[gm * H + h] = ps[h][rr];
                        a_dstO[gm * H + h] = pd[h][rr];
                    }
                }
            }
        }
    }
}

// ---------------- GAT aggregation, H=4: ONE WAVE PER NODE, zero barriers ----------------
__global__ void gat_agg4(const _Float16* __restrict__ h, const float* __restrict__ a_src,
                         const float* __restrict__ a_dst, const int* __restrict__ row_ptr,
                         const int* __restrict__ col, const float* __restrict__ bias,
                         _Float16* __restrict__ outp, int N) {
    int w = threadIdx.x >> 6, lane = threadIdx.x & 63;
    int i = blockIdx.x * 4 + w;
    if (i >= N) return;
    __shared__ float alphS[4][256];        // [wave][edge*4+head]
    __shared__ int   scolS[4][64];
    float* alph = alphS[w];
    int*   scol = scolS[w];
    int start = row_ptr[i], end = row_ptr[i + 1];
    int deg = end - start;
    float4 ad4 = *(const float4*)(a_dst + i * 4);
    int hh = lane >> 4;
    const _Float16* hb = h + lane * 4;     // per-lane column base (loop-invariant)
    float4 acc = make_float4(0.f, 0.f, 0.f, 0.f);

    if (deg <= 64) {
        float e0 = 0.f, e1 = 0.f, e2 = 0.f, e3 = 0.f; int s = 0;
        if (lane < deg) {
            s = col[start + lane];
            float4 as4 = *(const float4*)(a_src + (size_t)s * 4);
            e0 = __expf(leaky(as4.x + ad4.x));
            e1 = __expf(leaky(as4.y + ad4.y));
            e2 = __expf(leaky(as4.z + ad4.z));
            e3 = __expf(leaky(as4.w + ad4.w));
        }
        float s0 = wave_sum(e0), s1 = wave_sum(e1), s2 = wave_sum(e2), s3 = wave_sum(e3);
        if (lane < deg) {
            float4 al = make_float4(e0 / s0, e1 / s1, e2 / s2, e3 / s3);
            *(float4*)(alph + lane * 4) = al;
            scol[lane] = s;
        }
        // same-wave LDS RAW: hardware lgkmcnt ordering, no barrier needed
        int j = 0;
        for (; j + 3 < deg; j += 4) {
            int sA = __builtin_amdgcn_readfirstlane(scol[j]);
            int sB = __builtin_amdgcn_readfirstlane(scol[j + 1]);
            int sC = __builtin_amdgcn_readfirstlane(scol[j + 2]);
            int sD = __builtin_amdgcn_readfirstlane(scol[j + 3]);
            float aA = alph[j * 4 + hh],       aB = alph[(j + 1) * 4 + hh];
            float aC = alph[(j + 2) * 4 + hh], aD = alph[(j + 3) * 4 + hh];
            half4v vA = *(const half4v*)(hb + (size_t)sA * 256);
            half4v vB = *(const half4v*)(hb + (size_t)sB * 256);
            half4v vC = *(const half4v*)(hb + (size_t)sC * 256);
            half4v vD = *(const half4v*)(hb + (size_t)sD * 256);
            acc.x += aA * (float)vA[0] + aB * (float)vB[0] + aC * (float)vC[0] + aD * (float)vD[0];
            acc.y += aA * (float)vA[1] + aB * (float)vB[1] + aC * (float)vC[1] + aD * (float)vD[1];
            acc.z += aA * (float)vA[2] + aB * (float)vB[2] + aC * (float)vC[2] + aD * (float)vD[2];
            acc.w += aA * (float)vA[3] + aB * (float)vB[3] + aC * (float)vC[3] + aD * (float)vD[3];
        }
        for (; j < deg; ++j) {
            int sA = __builtin_amdgcn_readfirstlane(scol[j]);
            float aA = alph[j * 4 + hh];
            half4v vA = *(const half4v*)(hb + (size_t)sA * 256);
            acc.x += aA * (float)vA[0]; acc.y += aA * (float)vA[1];
            acc.z += aA * (float)vA[2]; acc.w += aA * (float)vA[3];
        }
    } else {
        float t0 = 0.f, t1 = 0.f, t2 = 0.f, t3 = 0.f;
        for (int j = start + lane; j < end; j += 64) {
            int s = col[j];
            float4 as4 = *(const float4*)(a_src + (size_t)s * 4);
            t0 += __expf(leaky(as4.x + ad4.x));
            t1 += __expf(leaky(as4.y + ad4.y));
            t2 += __expf(leaky(as4.z + ad4.z));
            t3 += __expf(leaky(as4.w + ad4.w));
        }
        t0 = wave_sum(t0); t1 = wave_sum(t1); t2 = wave_sum(t2); t3 = wave_sum(t3);
        float adh = (hh == 0) ? ad4.x : (hh == 1) ? ad4.y : (hh == 2) ? ad4.z : ad4.w;
        float ih  = 1.0f / ((hh == 0) ? t0 : (hh == 1) ? t1 : (hh == 2) ? t2 : t3);
        for (int j = start; j < end; ++j) {
            int s = col[j];                 // wave-uniform -> scalar load
            float asv = a_src[(size_t)s * 4 + hh];
            float alpha = __expf(leaky(asv + adh)) * ih;
            half4v v = *(const half4v*)(hb + (size_t)s * 256);
            acc.x += alpha * (float)v[0]; acc.y += alpha * (float)v[1];
            acc.z += alpha * (float)v[2]; acc.w += alpha * (float)v[3];
        }
    }
    float4 bv = *(const float4*)(bias + lane * 4);
    half4v o;
    o[0] = (_Float16)leaky(acc.x + bv.x);
    o[1] = (_Float16)leaky(acc.y + bv.y);
    o[2] = (_Float16)leaky(acc.z + bv.z);
    o[3] = (_Float16)leaky(acc.w + bv.w);
    *(half4v*)(outp + (size_t)i * 256 + lane * 4) = o;
}

// ---------------- GAT layer-2 aggregation + leaky + LayerNorm + residual, fused ----------
__global__ void gat_agg1_ln(const _Float16* __restrict__ h, const float* __restrict__ a_src,
                            const float* __restrict__ a_dst, const int* __restrict__ row_ptr,
                            const int* __restrict__ col, const float* __restrict__ bias,
                            const float* __restrict__ lin, const float* __restrict__ gamma,
                            const float* __restrict__ beta, _Float16* __restrict__ hresh,
                            int N) {
    int w = threadIdx.x >> 6, lane = threadIdx.x & 63;
    int i = blockIdx.x * 4 + w;
    if (i >= N) return;
    __shared__ float alphS[4][64];
    __shared__ int   scolS[4][64];
    float* alph = alphS[w];
    int*   scol = scolS[w];
    int start = row_ptr[i], end = row_ptr[i + 1];
    int deg = end - start;
    float ad = a_dst[i];
    int sub = lane >> 4;
    int c4 = (lane & 15) * 4;
    float4 acc = make_float4(0.f, 0.f, 0.f, 0.f);

    if (deg <= 64) {
        float e = 0.f; int s = 0;
        if (lane < deg) {
            s = col[start + lane];
            e = __expf(leaky(a_src[s] + ad));
        }
        float ss = wave_sum(e);
        if (lane < deg) { alph[lane] = e / ss; scol[lane] = s; }
        int j = sub;
        for (; j + 4 < deg; j += 8) {
            int s0 = scol[j], s1 = scol[j + 4];
            float a0 = alph[j], a1 = alph[j + 4];
            half4v v0 = *(const half4v*)(h + (size_t)s0 * 64 + c4);
            half4v v1 = *(const half4v*)(h + (size_t)s1 * 64 + c4);
            acc.x += a0 * (float)v0[0] + a1 * (float)v1[0];
            acc.y += a0 * (float)v0[1] + a1 * (float)v1[1];
            acc.z += a0 * (float)v0[2] + a1 * (float)v1[2];
            acc.w += a0 * (float)v0[3] + a1 * (float)v1[3];
        }
        for (; j < deg; j += 4) {
            int s = scol[j];
            float a0 = alph[j];
            half4v v = *(const half4v*)(h + (size_t)s * 64 + c4);
            acc.x += a0 * (float)v[0]; acc.y += a0 * (float)v[1];
            acc.z += a0 * (float)v[2]; acc.w += a0 * (float)v[3];
        }
    } else {
        float ssum = 0.f;
        for (int j = start + lane; j < end; j += 64)
            ssum += __expf(leaky(a_src[col[j]] + ad));
        ssum = wave_sum(ssum);
        float inv = 1.0f / ssum;
        for (int j = start + sub; j < end; j += 4) {
            int s = col[j];
            float alpha = __expf(leaky(a_src[s] + ad)) * inv;
            half4v v = *(const half4v*)(h + (size_t)s * 64 + c4);
            acc.x += alpha * (float)v[0]; acc.y += alpha * (float)v[1];
            acc.z += alpha * (float)v[2]; acc.w += alpha * (float)v[3];
        }
    }
    #pragma unroll
    for (int o = 16; o <= 32; o <<= 1) {
        acc.x += __shfl_xor(acc.x, o, 64);
        acc.y += __shfl_xor(acc.y, o, 64);
        acc.z += __shfl_xor(acc.z, o, 64);
        acc.w += __shfl_xor(acc.w, o, 64);
    }
    float4 bv = *(const float4*)(bias + c4);
    float o0 = leaky(acc.x + bv.x), o1 = leaky(acc.y + bv.y);
    float o2 = leaky(acc.z + bv.z), o3 = leaky(acc.w + bv.w);
    float ls = o0 + o1 + o2 + o3;
    #pragma unroll
    for (int o = 1; o <= 8; o <<= 1) ls += __shfl_xor(ls, o, 64);
    float mu = ls * (1.0f / 64.0f);
    float d0 = o0 - mu, d1 = o1 - mu, d2 = o2 - mu, d3 = o3 - mu;
    float lq = d0 * d0 + d1 * d1 + d2 * d2 + d3 * d3;
    #pragma unroll
    for (int o = 1; o <= 8; o <<= 1) lq += __shfl_xor(lq, o, 64);
    float rstd = rsqrtf(lq * (1.0f / 64.0f) + LN_EPS);
    float4 g4 = *(const float4*)(gamma + c4);
    float4 b4 = *(const float4*)(beta + c4);
    float4 l4 = *(const float4*)(lin + (size_t)i * 64 + c4);
    if (sub == 0) {
        half4v hv;
        hv[0] = (_Float16)(d0 * rstd * g4.x + b4.x + l4.x);
        hv[1] = (_Float16)(d1 * rstd * g4.y + b4.y + l4.y);
        hv[2] = (_Float16)(d2 * rstd * g4.z + b4.z + l4.z);
        hv[3] = (_Float16)(d3 * rstd * g4.w + b4.w + l4.w);
        *(half4v*)(hresh + (size_t)i * 64 + c4) = hv;
    }
}

// ---------------- gemm3 + GRU gates + FC head, fused (B through LDS) ----------------
__global__ __launch_bounds__(256, 2)
void gemm_gru(const _Float16* __restrict__ A, const _Float16* __restrict__ B,
              const float* __restrict__ b_ih, const float* __restrict__ b_hh,
              const float* __restrict__ fc_w, const float* __restrict__ fc_b,
              float* __restrict__ outp, int M) {
    const int K = 64, NT = 12, Nc = 192;
    constexpr int BROW = 40;
    __shared__ __align__(16) char smem[4 * 16 * 192 * 2];   // C-stage 24KB; B-tile 15KB aliased
    _Float16* sB = (_Float16*)smem;
    int tid = threadIdx.x;
    int w = tid >> 6, lane = tid & 63;
    int m_base = blockIdx.x * 64 + w * 16;
    bool active = (m_base < M);
    int r = lane & 15, q = lane >> 4;
    const _Float16* ap = A + (size_t)(m_base + r) * K + q * 8;
    floatx4 acc[NT];
    #pragma unroll
    for (int t = 0; t < NT; ++t) acc[t] = (floatx4){0.f, 0.f, 0.f, 0.f};
    half8 a_next = {};
    if (active) a_next = *(const half8*)ap;
    for (int k0 = 0; k0 < K; k0 += 32) {
        for (int i = tid; i < Nc * 4; i += 256) {
            int row = i >> 2, seg = i & 3;
            *(half8*)(sB + row * BROW + seg * 8) =
                *(const half8*)(B + (size_t)row * K + k0 + seg * 8);
        }
        __syncthreads();
        half8 a = a_next;
        if (active && k0 + 32 < K) a_next = *(const half8*)(ap + k0 + 32);
        if (active) {
            half8 b[NT];
            #pragma unroll
            for (int t = 0; t < NT; ++t)
                b[t] = *(const half8*)(sB + (t * 16 + r) * BROW + q * 8);
            #pragma unroll
            for (int t = 0; t < NT; ++t)
                acc[t] = __builtin_amdgcn_mfma_f32_16x16x32_f16(a, b[t], acc[t], 0, 0, 0);
        }
        __syncthreads();
    }
    if (!active) return;
    _Float16* sw = (_Float16*)smem + w * 16 * 192;
    #pragma unroll
    for (int t = 0; t < NT; ++t) {
        int cc = t * 16 + r;
        float bv = b_ih[cc];
        #pragma unroll
        for (int rr = 0; rr < 4; ++rr)
            sw[(q * 4 + rr) * Nc + cc] = (_Float16)(acc[t][rr] + bv);
    }
    // GRU + FC (same-wave LDS RAW — lgkmcnt ordering, no barrier)
    float br_[4], bz_[4], bn_[4], f0_[4], f1_[4], f2_[4];
    *(float4*)br_ = *(const float4*)(b_hh + r * 4);
    *(float4*)bz_ = *(const float4*)(b_hh + 64 + r * 4);
    *(float4*)bn_ = *(const float4*)(b_hh + 128 + r * 4);
    *(float4*)f0_ = *(const float4*)(fc_w + r * 4);
    *(float4*)f1_ = *(const float4*)(fc_w + 64 + r * 4);
    *(float4*)f2_ = *(const float4*)(fc_w + 128 + r * 4);
    #pragma unroll
    for (int rr = 0; rr < 4; ++rr) {
        int row = q * 4 + rr;
        const _Float16* g = sw + row * Nc;
        half4v ir4 = *(const half4v*)(g + r * 4);
        half4v iz4 = *(const half4v*)(g + 64 + r * 4);
        half4v in4 = *(const half4v*)(g + 128 + r * 4);
        float p0 = 0.f, p1 = 0.f, p2 = 0.f;
        #pragma unroll
        for (int k = 0; k < 4; ++k) {
            float rg = 1.0f / (1.0f + __expf(-((float)ir4[k] + br_[k])));
            float zg = 1.0f / (1.0f + __expf(-((float)iz4[k] + bz_[k])));
            float ng = tanhf((float)in4[k] + rg * bn_[k]);
            float hy = (1.0f - zg) * ng;
            p0 += hy * f0_[k]; p1 += hy * f1_[k]; p2 += hy * f2_[k];
        }
        #pragma unroll
        for (int o = 1; o <= 8; o <<= 1) {
            p0 += __shfl_xor(p0, o, 64);
            p1 += __shfl_xor(p1, o, 64);
            p2 += __shfl_xor(p2, o, 64);
        }
        if (r == 0) {
            int gm = m_base + row;
            outp[(size_t)gm * 3 + 0] = p0 + fc_b[0];
            outp[(size_t)gm * 3 + 1] = p1 + fc_b[1];
            outp[(size_t)gm * 3 + 2] = p2 + fc_b[2];
        }
    }
}

extern "C" void kernel_launch(void* const* d_in, const int* in_sizes, int n_in,
                              void* d_out, int out_size, void* d_ws, size_t ws_size,
                              hipStream_t stream) {
    const float* x        = (const float*)d_in[0];
    const int*   ei       = (const int*)d_in[1];
    const float* W1       = (const float*)d_in[2];
    const float* att_src1 = (const float*)d_in[3];
    const float* att_dst1 = (const float*)d_in[4];
    const float* b1       = (const float*)d_in[5];
    const float* W2       = (const float*)d_in[6];
    const float* att_src2 = (const float*)d_in[7];
    const float* att_dst2 = (const float*)d_in[8];
    const float* b2       = (const float*)d_in[9];
    const float* lin_w    = (const float*)d_in[10];
    const float* lin_b    = (const float*)d_in[11];
    const float* gamma    = (const float*)d_in[12];
    const float* beta     = (const float*)d_in[13];
    const float* w_ih     = (const float*)d_in[14];
    // d_in[15] = w_hh (unused: h0 == 0)
    const float* b_ih     = (const float*)d_in[16];
    const float* b_hh     = (const float*)d_in[17];
    const float* fc_w     = (const float*)d_in[18];
    const float* fc_b     = (const float*)d_in[19];
    float* out = (float*)d_out;

    const int N = N_NODES, E = N_EDGES;
    const int Etot = E + N;
    const int nb = (N + 255) / 256;       // 196 scan blocks
    char* ws = (char*)d_ws;

    size_t off = 0;
    auto alloc = [&](size_t bytes) {
        size_t o = off;
        off = (off + bytes + 255) & ~(size_t)255;
        return o;
    };
    int*      row_ptr = (int*)(ws + alloc((size_t)(N + 1) * 4));
    int*      col     = (int*)(ws + alloc((size_t)Etot * 4));
    int*      deg     = (int*)(ws + alloc((size_t)N * 4));
    int*      fill    = (int*)(ws + alloc((size_t)N * 4));
    int*      bsum    = (int*)(ws + alloc((size_t)nb * 4));
    float*    a_src1b = (float*)(ws + alloc((size_t)N * HEADS * 4));
    float*    a_dst1b = (float*)(ws + alloc((size_t)N * HEADS * 4));
    float*    a_src2b = (float*)(ws + alloc((size_t)N * 4));
    float*    a_dst2b = (float*)(ws + alloc((size_t)N * 4));
    _Float16* W1h     = (_Float16*)(ws + alloc((size_t)256 * 256 * 2));
    _Float16* W2h     = (_Float16*)(ws + alloc((size_t)64 * 256 * 2));
    _Float16* lin_wh  = (_Float16*)(ws + alloc((size_t)64 * 256 * 2));
    _Float16* w_ihh   = (_Float16*)(ws + alloc((size_t)192 * 64 * 2));
    // big region (64MB): xh@0 (25.6M), h1h@25.6M (25.6M), lin@51.2M (12.8M fp32).
    char* big = ws + alloc((size_t)64000000);
    _Float16* xh   = (_Float16*)big;
    _Float16* h1h  = (_Float16*)(big + 25600000);
    float*    lin  = (float*)(big + 51200000);
    // region r3 (25.6M): o1h (fp16 [N,256]); after gemm2 consumes it -> hresh (fp16 [N,64])
    char* r3 = ws + alloc((size_t)25600000);
    _Float16* o1h   = (_Float16*)r3;
    _Float16* hresh = (_Float16*)r3;
    // region r4 (6.4M): h2h (fp16 [N,64])
    char* r4 = ws + alloc((size_t)6400000);
    _Float16* h2h = (_Float16*)r4;

    hipMemsetAsync(deg, 0, (size_t)N * 4, stream);
    hipMemsetAsync(fill, 0, (size_t)N * 4, stream);

    // ---- CSR build ----
    count_kernel<<<(Etot + 255) / 256, 256, 0, stream>>>(ei + E, deg, E, Etot);
    scan_part<<<nb, 256, 0, stream>>>(deg, bsum, N);
    scan_top<<<1, 256, 0, stream>>>(bsum, nb);
    scan_final<<<nb, 256, 0, stream>>>(deg, bsum, row_ptr, N);
    scatter_kernel<<<(Etot + 255) / 256, 256, 0, stream>>>(ei, ei + E, row_ptr, fill, col, E, Etot);

    // ---- fp16 conversions (one kernel, 5 ranges) ----
    {
        CvtJob j0{x, xh, N * F_IN};
        CvtJob j1{W1, W1h, 256 * 256};
        CvtJob j2{W2, W2h, 64 * 256};
        CvtJob j3{lin_w, lin_wh, 64 * 256};
        CvtJob j4{w_ih, w_ihh, 192 * 64};
        int total4 = (j0.len + j1.len + j2.len + j3.len + j4.len) / 4;
        cvt_f16_multi<<<(total4 + 255) / 256, 256, 0, stream>>>(j0, j1, j2, j3, j4);
    }

    const int gmBlocks = (N + 63) / 64;   // 782
    const int aggBlocks = (N + 3) / 4;    // 12500 (one wave per node)

    // ---- GAT layer 1 GEMM (+att coefs) ----
    gemm_mfma<16, 4, _Float16><<<gmBlocks, 256, 0, stream>>>(xh, W1h, nullptr, h1h,
        att_src1, att_dst1, a_src1b, a_dst1b, N, 256, 0);
    gat_agg4<<<aggBlocks, 256, 0, stream>>>(h1h, a_src1b, a_dst1b, row_ptr, col, b1, o1h, N);

    // ---- residual projection: lin = x @ lin_w^T + lin_b (fp32 out) ----
    gemm_mfma<4, 0, float><<<gmBlocks, 256, 0, stream>>>(xh, lin_wh, lin_b, lin,
        nullptr, nullptr, nullptr, nullptr, N, 256, 1);

    // ---- GAT layer 2 GEMM (+att coefs) ----
    gemm_mfma<4, 1, _Float16><<<gmBlocks, 256, 0, stream>>>(o1h, W2h, nullptr, h2h,
        att_src2, att_dst2, a_src2b, a_dst2b, N, 256, 0);

    // ---- layer-2 aggregation + leaky + LN + residual -> hresh fp16 (fused) ----
    gat_agg1_ln<<<aggBlocks, 256, 0, stream>>>(h2h, a_src2b, a_dst2b, row_ptr, col, b2,
        lin, gamma, beta, hresh, N);

    // ---- GRU input GEMM + gates + FC head (fused) ----
    gemm_gru<<<gmBlocks, 256, 0, stream>>>(hresh, w_ihh, b_ih, b_hh, fc_w, fc_b, out, N);
}